// Round 7
// baseline (288.002 us; speedup 1.0000x reference)
//
#include <hip/hip_runtime.h>

#define NN 100000
#define NE 1600000
#define DF 128
#define NBUCK 391     // ceil(NN/256); bucket b = dst >> 8
#define PB_BLOCKS 196 // ceil(NE / 8192)
#define CX_BLOCKS 6250 // NN*DF/8 / 256
#define CW_BLOCKS 128

typedef short short8 __attribute__((ext_vector_type(8)));
typedef float floatx4 __attribute__((ext_vector_type(4)));
typedef float floatx2 __attribute__((ext_vector_type(2)));
typedef unsigned int uintx4 __attribute__((ext_vector_type(4)));
typedef unsigned int uint;
typedef unsigned short ushort;
typedef unsigned char uchar;

// float -> bf16 (RNE; inputs finite)
static __device__ __forceinline__ ushort f2bf(float f) {
    uint u = __builtin_bit_cast(uint, f);
    return (ushort)((u + 0x7fffu + ((u >> 16) & 1u)) >> 16);
}

// ---------------------------------------------------------------------------
// Fused pre-pass: three independent jobs in one dispatch (block-range split)
//   [0, CX)        conv_x: SLAB-LINEAR mapping. j -> (p, node, q2): fp8 write
//                  is fully sequential, bf16 write is 64B-line complete,
//                  x read is 32B/lane in 128B runs. (R6: node-major mapping
//                  made slab writes 32B partial-line -> fused_pre 2.7x roofline)
//   [CX, CX+CW)    conv_w: W^T bf16 build
//   [CX+CW, ...)   pA: bucket histogram (LDS-aggregated)
// ---------------------------------------------------------------------------
__global__ __launch_bounds__(256) void fused_pre(
        const float* __restrict__ x, ushort* __restrict__ xb, uint* __restrict__ xf8c,
        const float* __restrict__ W1l, const float* __restrict__ W1r,
        const float* __restrict__ W2l, const float* __restrict__ W2r,
        ushort* __restrict__ WT1, ushort* __restrict__ WT2,
        const int* __restrict__ dst, int* __restrict__ gcnt) {
    __shared__ int h[NBUCK];
    int bid = blockIdx.x;
    int tid = threadIdx.x;
    if (bid < CX_BLOCKS) {
        int j = bid * 256 + tid;            // 0 .. NN*DF/8-1, slab-linear
        int p = j / (NN * 4);
        int rem = j - p * (NN * 4);
        int node = rem >> 2, q2 = rem & 3;
        const float4* xr = (const float4*)(x + (size_t)node * 128 + p * 32 + q2 * 8);
        float4 v0 = xr[0], v1 = xr[1];
        uint4 ob;
        ob.x = (uint)f2bf(v0.x) | ((uint)f2bf(v0.y) << 16);
        ob.y = (uint)f2bf(v0.z) | ((uint)f2bf(v0.w) << 16);
        ob.z = (uint)f2bf(v1.x) | ((uint)f2bf(v1.y) << 16);
        ob.w = (uint)f2bf(v1.z) | ((uint)f2bf(v1.w) << 16);
        *(uint4*)(xb + (size_t)node * 128 + p * 32 + q2 * 8) = ob;
        uint pk0 = (uint)__builtin_amdgcn_cvt_pk_fp8_f32(v0.x, v0.y, 0, false);
        pk0 = (uint)__builtin_amdgcn_cvt_pk_fp8_f32(v0.z, v0.w, (int)pk0, true);
        uint pk1 = (uint)__builtin_amdgcn_cvt_pk_fp8_f32(v1.x, v1.y, 0, false);
        pk1 = (uint)__builtin_amdgcn_cvt_pk_fp8_f32(v1.z, v1.w, (int)pk1, true);
        ((uint2*)xf8c)[j] = make_uint2(pk0, pk1);
    } else if (bid < CX_BLOCKS + CW_BLOCKS) {
        int id = (bid - CX_BLOCKS) * 256 + tid;
        int n = id >> 8, k = id & 255;
        float a = (k < 128) ? W1l[k * 128 + n] : W1r[(k - 128) * 128 + n];
        float b = (k < 128) ? W2l[k * 128 + n] : W2r[(k - 128) * 128 + n];
        WT1[id] = f2bf(a);
        WT2[id] = f2bf(b);
    } else {
        int blk = bid - CX_BLOCKS - CW_BLOCKS;
        for (int i = tid; i < NBUCK; i += 256) h[i] = 0;
        __syncthreads();
        int eb = blk * 8192 + tid;
        #pragma unroll
        for (int k = 0; k < 32; ++k) {
            int e = eb + k * 256;
            if (e < NE) atomicAdd(&h[dst[e] >> 8], 1);
        }
        __syncthreads();
        for (int i = tid; i < NBUCK; i += 256)
            if (h[i]) atomicAdd(&gcnt[i], h[i]);
    }
}

// Pass S: exclusive scan of bucket counts -> goff (bucket base in srt); gcur=goff.
__global__ __launch_bounds__(512) void pS_scan(const int* __restrict__ gcnt,
                                               int* __restrict__ goff,
                                               int* __restrict__ gcur) {
    __shared__ int s[512];
    int tid = threadIdx.x;
    int v = (tid < NBUCK) ? gcnt[tid] : 0;
    s[tid] = v;
    __syncthreads();
    for (int st = 1; st < 512; st <<= 1) {
        int t = (tid >= st) ? s[tid - st] : 0;
        __syncthreads();
        s[tid] += t;
        __syncthreads();
    }
    if (tid < NBUCK) {
        int e = s[tid] - v;
        goff[tid] = e;
        gcur[tid] = e;
    }
    if (tid == 0) goff[NBUCK] = NE;
}

// Pass B: partition (src,dst) pairs bucket-contiguous. Per-block LDS ranks;
// one global atomicAdd per (block,bucket). Writes land in ~170B runs.
__global__ __launch_bounds__(512) void pB_part(const int* __restrict__ src,
                                               const int* __restrict__ dst,
                                               int* __restrict__ gcur,
                                               uint2* __restrict__ pairs) {
    __shared__ int h[NBUCK];
    __shared__ int base[NBUCK];
    for (int i = threadIdx.x; i < NBUCK; i += 512) h[i] = 0;
    __syncthreads();
    int eb = blockIdx.x * 8192 + threadIdx.x;
    int bkt[16], dv[16];
    #pragma unroll
    for (int k = 0; k < 16; ++k) {
        int e = eb + k * 512;
        bkt[k] = -1;
        if (e < NE) {
            int d = dst[e];
            dv[k] = d;
            bkt[k] = d >> 8;
            atomicAdd(&h[bkt[k]], 1);
        }
    }
    __syncthreads();
    for (int i = threadIdx.x; i < NBUCK; i += 512) {
        base[i] = h[i] ? atomicAdd(&gcur[i], h[i]) : 0;
        h[i] = 0;
    }
    __syncthreads();
    #pragma unroll
    for (int k = 0; k < 16; ++k) {
        int e = eb + k * 512;
        if (e < NE) {
            int r = atomicAdd(&h[bkt[k]], 1);
            pairs[base[bkt[k]] + r] = make_uint2((uint)src[e], (uint)dv[k]);
        }
    }
}

// Pass C: one block per bucket. LDS degree count + scan -> off[] (coalesced),
// then scatter src into the bucket's ~16KB srt window. Also emits an
// LDS-aggregated degree histogram (64 classes) for the degree-sort perm.
__global__ __launch_bounds__(256) void pC_scatter(const uint2* __restrict__ pairs,
                                                  const int* __restrict__ goff,
                                                  int* __restrict__ off,
                                                  int* __restrict__ srt,
                                                  int* __restrict__ dhist) {
    __shared__ int deg[256];
    __shared__ int loc[256];
    __shared__ int dh[64];
    int b = blockIdx.x;
    int beg = goff[b], end = goff[b + 1];
    int tid = threadIdx.x;
    deg[tid] = 0;
    if (tid < 64) dh[tid] = 0;
    __syncthreads();
    for (int i = beg + tid; i < end; i += 256)
        atomicAdd(&deg[pairs[i].y & 255], 1);
    __syncthreads();
    int v = deg[tid];
    int n = (b << 8) + tid;
    if (n < NN) atomicAdd(&dh[v < 63 ? v : 63], 1);
    loc[tid] = v;
    __syncthreads();
    for (int st = 1; st < 256; st <<= 1) {
        int t = (tid >= st) ? loc[tid - st] : 0;
        __syncthreads();
        loc[tid] += t;
        __syncthreads();
    }
    int excl = loc[tid] - v + beg;     // global CSR offset for node (b<<8)+tid
    if (n < NN) off[n] = excl;
    __syncthreads();
    deg[tid] = excl;                   // reuse as cursor
    __syncthreads();
    for (int i = beg + tid; i < end; i += 256) {
        uint2 pr = pairs[i];
        int pos = atomicAdd(&deg[pr.y & 255], 1);
        srt[pos] = (int)pr.x;
    }
    if (tid < 64 && dh[tid]) atomicAdd(&dhist[tid], dh[tid]);
}

// Pass D: exclusive scan of 64 degree-class counts -> dcur (class bases).
__global__ void pD_scan(const int* __restrict__ dhist, int* __restrict__ dcur) {
    __shared__ int s[64];
    int tid = threadIdx.x;
    int v = dhist[tid];
    s[tid] = v;
    __syncthreads();
    for (int st = 1; st < 64; st <<= 1) {
        int t = (tid >= st) ? s[tid - st] : 0;
        __syncthreads();
        s[tid] += t;
        __syncthreads();
    }
    dcur[tid] = s[tid] - v;
}

// Pass E: degree-sorted permutation (block-ranked counting sort, pB pattern).
// agg waves then process 16 SAME-degree nodes -> no max-deg divergence.
__global__ __launch_bounds__(256) void pE_perm(const int* __restrict__ off,
                                               int* __restrict__ dcur,
                                               int* __restrict__ perm) {
    __shared__ int h[64];
    __shared__ int base[64];
    int tid = threadIdx.x;
    int n = blockIdx.x * 256 + tid;
    if (tid < 64) h[tid] = 0;
    __syncthreads();
    int cls = 0, r = 0;
    if (n < NN) {
        int d = ((n < NN - 1) ? off[n + 1] : NE) - off[n];
        cls = d < 63 ? d : 63;
        r = atomicAdd(&h[cls], 1);
    }
    __syncthreads();
    if (tid < 64) base[tid] = h[tid] ? atomicAdd(&dcur[tid], h[tid]) : 0;
    __syncthreads();
    if (n < NN) perm[base[cls] + r] = n;
}

// ---------------------------------------------------------------------------
// Mean aggregation, CSR + chunked + degree-sorted. One dispatch per 32-column
// fp8 chunk p (3.2MB slab, L2-resident). 4 lanes per node (uint2 = 8 fp8 each),
// unroll x4. Nodes taken through perm[] so each wave's 16 nodes have equal
// degree. aggb row-write is one full 64B line -> no scatter amplification.
// ---------------------------------------------------------------------------
static __device__ __forceinline__ void acc8(floatx2* ac, uint2 v) {
    ac[0] += __builtin_amdgcn_cvt_pk_f32_fp8((int)v.x, false);
    ac[1] += __builtin_amdgcn_cvt_pk_f32_fp8((int)v.x, true);
    ac[2] += __builtin_amdgcn_cvt_pk_f32_fp8((int)v.y, false);
    ac[3] += __builtin_amdgcn_cvt_pk_f32_fp8((int)v.y, true);
}

__global__ __launch_bounds__(256) void agg_csr(const uint* __restrict__ feat8,
                                               const int* __restrict__ srt,
                                               const int* __restrict__ off,
                                               const int* __restrict__ perm,
                                               ushort* __restrict__ aggb, int p) {
    int slot = blockIdx.x * 64 + (threadIdx.x >> 2);
    int l = threadIdx.x & 3;
    if (slot >= NN) return;
    int n = perm[slot];
    const uint2* f = (const uint2*)(feat8 + (size_t)p * (NN * 8)) + l;

    int beg = off[n];
    int end = (n < NN - 1) ? off[n + 1] : NE;

    floatx2 ac[4];
    #pragma unroll
    for (int t = 0; t < 4; ++t) ac[t] = (floatx2){0.f, 0.f};

    int i = beg;
    for (; i + 4 <= end; i += 4) {
        int i0 = srt[i], i1 = srt[i + 1], i2 = srt[i + 2], i3 = srt[i + 3];
        uint2 v0 = f[(size_t)i0 * 4];
        uint2 v1 = f[(size_t)i1 * 4];
        uint2 v2 = f[(size_t)i2 * 4];
        uint2 v3 = f[(size_t)i3 * 4];
        acc8(ac, v0);
        acc8(ac, v1);
        acc8(ac, v2);
        acc8(ac, v3);
    }
    for (; i < end; ++i) {
        uint2 v = f[(size_t)srt[i] * 4];
        acc8(ac, v);
    }

    float inv = 1.0f / fmaxf((float)(end - beg), 1.0f);
    uintx4 o;
    o.x = (uint)f2bf(ac[0].x * inv) | ((uint)f2bf(ac[0].y * inv) << 16);
    o.y = (uint)f2bf(ac[1].x * inv) | ((uint)f2bf(ac[1].y * inv) << 16);
    o.z = (uint)f2bf(ac[2].x * inv) | ((uint)f2bf(ac[2].y * inv) << 16);
    o.w = (uint)f2bf(ac[3].x * inv) | ((uint)f2bf(ac[3].y * inv) << 16);
    uintx4* dp = (uintx4*)(aggb + (size_t)n * 128 + p * 32 + l * 8);
    __builtin_nontemporal_store(o, dp);
}

// ---------------------------------------------------------------------------
// Fused GEMM: C[n,j] = act( [agg|self][n,:] @ WT[j,:] + bias[j] ), K=256.
// 512 threads = 8 waves, 128 rows/block. WT staged in LDS (XOR swizzle, 64KB).
// F8OUT: also emit fp8 chunk-major (layer-2 agg input) -> conv_h eliminated.
// ---------------------------------------------------------------------------
template <int RELU, int BF16OUT, int F8OUT>
__global__ __launch_bounds__(512, 4) void gemm_mfma(
        const ushort* __restrict__ aggb, const ushort* __restrict__ selfb,
        const ushort* __restrict__ WT, const float* __restrict__ bias,
        void* __restrict__ outv, uchar* __restrict__ f8out) {
    __shared__ ushort sWT[128 * 256];            // 64KB, swizzled chunks
    const int tid = threadIdx.x;
    const int blk = blockIdx.x;

    #pragma unroll
    for (int it = 0; it < 8; ++it) {
        int flat = it * 512 + tid;               // 0..4095
        int col = flat >> 5;
        int c = flat & 31;
        uint4 v = *(const uint4*)(WT + (size_t)col * 256 + c * 8);
        *(uint4*)&sWT[col * 256 + (c ^ (col & 7)) * 8] = v;
    }

    const int w = tid >> 6;
    const int lane = tid & 63;
    const int m = lane & 15;
    const int q = lane >> 4;

    int node_m = blk * 128 + w * 16 + m;
    int cn = node_m < NN ? node_m : NN - 1;
    const ushort* arow = aggb + (size_t)cn * 128;
    const ushort* xrow = selfb + (size_t)cn * 128;
    short8 a[8];
    #pragma unroll
    for (int kk = 0; kk < 4; ++kk) {
        a[kk]     = *(const short8*)(arow + kk * 32 + q * 8);
        a[4 + kk] = *(const short8*)(xrow + kk * 32 + q * 8);
    }

    __syncthreads();

    floatx4 acc[8];
    #pragma unroll
    for (int t = 0; t < 8; ++t) acc[t] = (floatx4){0.f, 0.f, 0.f, 0.f};

    const int m7 = m & 7;
    #pragma unroll
    for (int kk = 0; kk < 8; ++kk) {
        int cx = (kk * 4 + q) ^ m7;
        #pragma unroll
        for (int t = 0; t < 8; ++t) {
            short8 b = *(const short8*)&sWT[(t * 16 + m) * 256 + cx * 8];
            acc[t] = __builtin_amdgcn_mfma_f32_16x16x32_bf16(a[kk], b, acc[t], 0, 0, 0);
        }
    }

    const int node_base = blk * 128 + w * 16 + q * 4;
    #pragma unroll
    for (int t = 0; t < 8; ++t) {
        int col = t * 16 + m;
        float bj = bias[col];
        #pragma unroll
        for (int r = 0; r < 4; ++r) {
            int node = node_base + r;
            if (node < NN) {
                float v = acc[t][r] + bj;
                if (RELU) v = fmaxf(v, 0.0f);
                if (BF16OUT)
                    ((ushort*)outv)[(size_t)node * 128 + col] = f2bf(v);
                else
                    ((float*)outv)[(size_t)node * 128 + col] = v;
                if (F8OUT) {
                    uint pk = (uint)__builtin_amdgcn_cvt_pk_fp8_f32(v, v, 0, false);
                    f8out[((size_t)(col >> 5) * NN + node) * 32 + (col & 31)] =
                        (uchar)pk;
                }
            }
        }
    }
}

// ---------------------------------------------------------------------------
extern "C" void kernel_launch(void* const* d_in, const int* in_sizes, int n_in,
                              void* d_out, int out_size, void* d_ws, size_t ws_size,
                              hipStream_t stream) {
    const float* x   = (const float*)d_in[0];
    const int*   ei  = (const int*)d_in[1];
    const float* W1l = (const float*)d_in[2];
    const float* b1  = (const float*)d_in[3];
    const float* W1r = (const float*)d_in[4];
    const float* W2l = (const float*)d_in[5];
    const float* b2  = (const float*)d_in[6];
    const float* W2r = (const float*)d_in[7];
    float*       out = (float*)d_out;

    const int* src = ei;
    const int* dst = ei + NE;

    // workspace layout (bytes), total 96.93 MB
    char* ws = (char*)d_ws;
    int*    off  = (int*)(ws);                   // 400000
    int*    srt  = (int*)(ws + 400000);          // 6400000 (ends 6.8MB)
    int*    perm = (int*)(ws + 6800000);         // 400000 (ends 7.2MB)
    ushort* WT1  = (ushort*)(ws + 7200000);      // 65536
    ushort* WT2  = (ushort*)(ws + 7265536);      // 65536
    ushort* xb   = (ushort*)(ws + 7331072);      // 25600000
    uint*   xf8c = (uint*)(ws + 32931072);       // 12800000 (chunk-major fp8)
    ushort* aggb = (ushort*)(ws + 45731072);     // 25600000
    ushort* hb   = (ushort*)(ws + 71331072);     // 25600000 (end 96.93MB)
    uchar*  hf8c = (uchar*)xf8c;                 // alias: xf8c dead after agg L1
    // CSR-build temporaries, all dead before aggb is written:
    uint2*  pairs = (uint2*)aggb;                       // 12800000
    int*    gcnt  = (int*)((char*)aggb + 12800000);     // 1564
    int*    goff  = (int*)((char*)aggb + 12801600);     // 1568
    int*    gcur  = (int*)((char*)aggb + 12803200);     // 1564
    int*    dhist = (int*)((char*)aggb + 12804800);     // 256
    int*    dcur  = (int*)((char*)aggb + 12805120);     // 256

    // ---- CSR build + input conversion ----
    (void)hipMemsetAsync(gcnt, 0, 6144, stream);  // gcnt + dhist(+slack)
    fused_pre<<<CX_BLOCKS + CW_BLOCKS + PB_BLOCKS, 256, 0, stream>>>(
        x, xb, xf8c, W1l, W1r, W2l, W2r, WT1, WT2, dst, gcnt);
    pS_scan<<<1, 512, 0, stream>>>(gcnt, goff, gcur);
    pB_part<<<PB_BLOCKS, 512, 0, stream>>>(src, dst, gcur, pairs);
    pC_scatter<<<NBUCK, 256, 0, stream>>>(pairs, goff, off, srt, dhist);
    pD_scan<<<1, 64, 0, stream>>>(dhist, dcur);
    pE_perm<<<NBUCK, 256, 0, stream>>>(off, dcur, perm);

    const int gemm_grid = (NN + 127) / 128;
    const int agg_grid = (NN + 63) / 64;

    // ---- layer 1 ----  (4 serialized chunk passes keep each 3.2MB slab L2-hot)
    for (int p = 0; p < 4; ++p)
        agg_csr<<<agg_grid, 256, 0, stream>>>(xf8c, srt, off, perm, aggb, p);
    gemm_mfma<1, 1, 1><<<gemm_grid, 512, 0, stream>>>(aggb, xb, WT1, b1, hb, hf8c);

    // ---- layer 2 ----
    for (int p = 0; p < 4; ++p)
        agg_csr<<<agg_grid, 256, 0, stream>>>((const uint*)hf8c, srt, off, perm, aggb, p);
    gemm_mfma<0, 0, 0><<<gemm_grid, 512, 0, stream>>>(aggb, hb, WT2, b2, out, nullptr);
}

// Round 8
// 243.003 us; speedup vs baseline: 1.1852x; 1.1852x over previous
//
#include <hip/hip_runtime.h>

#define NN 100000
#define NE 1600000
#define DF 128
#define NBUCK 391      // ceil(NN/256); bucket b = dst >> 8
#define PA_BLOCKS 784  // ceil(NE / 2048), 8 edges/thread @256
#define PB_BLOCKS 391  // ceil(NE / 4096), 8 edges/thread @512
#define CX_BLOCKS 6250 // NN*DF/8 / 256
#define CW_BLOCKS 128
#define AGG_GRID 1563  // ceil(NN/64)

typedef short short8 __attribute__((ext_vector_type(8)));
typedef float floatx4 __attribute__((ext_vector_type(4)));
typedef float floatx2 __attribute__((ext_vector_type(2)));
typedef unsigned int uintx4 __attribute__((ext_vector_type(4)));
typedef unsigned int uint;
typedef unsigned short ushort;
typedef unsigned char uchar;

// float -> bf16 (RNE; inputs finite)
static __device__ __forceinline__ ushort f2bf(float f) {
    uint u = __builtin_bit_cast(uint, f);
    return (ushort)((u + 0x7fffu + ((u >> 16) & 1u)) >> 16);
}

// ---------------------------------------------------------------------------
// Fused pre-pass, block-range split. pA FIRST: R7 counters showed fused_pre
// latency-bound on the 196 tail histogram blocks (1 blk/CU, 32 serial
// load+LDS-atomic iters, no TLP). Now 784 pA blocks dispatch before conv_x
// so they overlap it and have 3 blocks/CU.
//   [0, PA)            pA: bucket histogram (LDS-aggregated, 8 edges/thread)
//   [PA, PA+CX)        conv_x: x fp32 -> xb bf16 + xf8c fp8 slab-linear
//   [PA+CX, +CW)       conv_w: W^T bf16 build
// ---------------------------------------------------------------------------
__global__ __launch_bounds__(256) void fused_pre(
        const float* __restrict__ x, ushort* __restrict__ xb, uint* __restrict__ xf8c,
        const float* __restrict__ W1l, const float* __restrict__ W1r,
        const float* __restrict__ W2l, const float* __restrict__ W2r,
        ushort* __restrict__ WT1, ushort* __restrict__ WT2,
        const int* __restrict__ dst, int* __restrict__ gcnt) {
    __shared__ int h[NBUCK];
    int bid = blockIdx.x;
    int tid = threadIdx.x;
    if (bid < PA_BLOCKS) {
        for (int i = tid; i < NBUCK; i += 256) h[i] = 0;
        __syncthreads();
        int eb = bid * 2048 + tid;
        #pragma unroll
        for (int k = 0; k < 8; ++k) {
            int e = eb + k * 256;
            if (e < NE) atomicAdd(&h[dst[e] >> 8], 1);
        }
        __syncthreads();
        for (int i = tid; i < NBUCK; i += 256)
            if (h[i]) atomicAdd(&gcnt[i], h[i]);
    } else if (bid < PA_BLOCKS + CX_BLOCKS) {
        int j = (bid - PA_BLOCKS) * 256 + tid;  // 0 .. NN*DF/8-1, slab-linear
        int p = j / (NN * 4);
        int rem = j - p * (NN * 4);
        int node = rem >> 2, q2 = rem & 3;
        const float4* xr = (const float4*)(x + (size_t)node * 128 + p * 32 + q2 * 8);
        float4 v0 = xr[0], v1 = xr[1];
        uint4 ob;
        ob.x = (uint)f2bf(v0.x) | ((uint)f2bf(v0.y) << 16);
        ob.y = (uint)f2bf(v0.z) | ((uint)f2bf(v0.w) << 16);
        ob.z = (uint)f2bf(v1.x) | ((uint)f2bf(v1.y) << 16);
        ob.w = (uint)f2bf(v1.z) | ((uint)f2bf(v1.w) << 16);
        *(uint4*)(xb + (size_t)node * 128 + p * 32 + q2 * 8) = ob;
        uint pk0 = (uint)__builtin_amdgcn_cvt_pk_fp8_f32(v0.x, v0.y, 0, false);
        pk0 = (uint)__builtin_amdgcn_cvt_pk_fp8_f32(v0.z, v0.w, (int)pk0, true);
        uint pk1 = (uint)__builtin_amdgcn_cvt_pk_fp8_f32(v1.x, v1.y, 0, false);
        pk1 = (uint)__builtin_amdgcn_cvt_pk_fp8_f32(v1.z, v1.w, (int)pk1, true);
        ((uint2*)xf8c)[j] = make_uint2(pk0, pk1);
    } else {
        int id = (bid - PA_BLOCKS - CX_BLOCKS) * 256 + tid;
        int n = id >> 8, k = id & 255;
        float a = (k < 128) ? W1l[k * 128 + n] : W1r[(k - 128) * 128 + n];
        float b = (k < 128) ? W2l[k * 128 + n] : W2r[(k - 128) * 128 + n];
        WT1[id] = f2bf(a);
        WT2[id] = f2bf(b);
    }
}

// Pass S: exclusive scan of bucket counts -> goff (bucket base in srt); gcur=goff.
__global__ __launch_bounds__(512) void pS_scan(const int* __restrict__ gcnt,
                                               int* __restrict__ goff,
                                               int* __restrict__ gcur) {
    __shared__ int s[512];
    int tid = threadIdx.x;
    int v = (tid < NBUCK) ? gcnt[tid] : 0;
    s[tid] = v;
    __syncthreads();
    for (int st = 1; st < 512; st <<= 1) {
        int t = (tid >= st) ? s[tid - st] : 0;
        __syncthreads();
        s[tid] += t;
        __syncthreads();
    }
    if (tid < NBUCK) {
        int e = s[tid] - v;
        goff[tid] = e;
        gcur[tid] = e;
    }
    if (tid == 0) goff[NBUCK] = NE;
}

// Pass B: partition (src,dst) pairs bucket-contiguous. Per-block LDS ranks;
// one global atomicAdd per (block,bucket). 8 edges/thread, 391 blocks.
__global__ __launch_bounds__(512) void pB_part(const int* __restrict__ src,
                                               const int* __restrict__ dst,
                                               int* __restrict__ gcur,
                                               uint2* __restrict__ pairs) {
    __shared__ int h[NBUCK];
    __shared__ int base[NBUCK];
    for (int i = threadIdx.x; i < NBUCK; i += 512) h[i] = 0;
    __syncthreads();
    int eb = blockIdx.x * 4096 + threadIdx.x;
    int bkt[8], dv[8];
    #pragma unroll
    for (int k = 0; k < 8; ++k) {
        int e = eb + k * 512;
        bkt[k] = -1;
        if (e < NE) {
            int d = dst[e];
            dv[k] = d;
            bkt[k] = d >> 8;
            atomicAdd(&h[bkt[k]], 1);
        }
    }
    __syncthreads();
    for (int i = threadIdx.x; i < NBUCK; i += 512) {
        base[i] = h[i] ? atomicAdd(&gcur[i], h[i]) : 0;
        h[i] = 0;
    }
    __syncthreads();
    #pragma unroll
    for (int k = 0; k < 8; ++k) {
        int e = eb + k * 512;
        if (e < NE) {
            int r = atomicAdd(&h[bkt[k]], 1);
            pairs[base[bkt[k]] + r] = make_uint2((uint)src[e], (uint)dv[k]);
        }
    }
}

// Pass C: one block per bucket. LDS degree count + scan -> off[] (coalesced),
// then scatter src into the bucket's ~16KB srt window (single-XCD dirtying,
// no write amplification). Second pairs read is L2-hot.
__global__ __launch_bounds__(256) void pC_scatter(const uint2* __restrict__ pairs,
                                                  const int* __restrict__ goff,
                                                  int* __restrict__ off,
                                                  int* __restrict__ srt) {
    __shared__ int deg[256];
    __shared__ int loc[256];
    int b = blockIdx.x;
    int beg = goff[b], end = goff[b + 1];
    int tid = threadIdx.x;
    deg[tid] = 0;
    __syncthreads();
    for (int i = beg + tid; i < end; i += 256)
        atomicAdd(&deg[pairs[i].y & 255], 1);
    __syncthreads();
    int v = deg[tid];
    loc[tid] = v;
    __syncthreads();
    for (int st = 1; st < 256; st <<= 1) {
        int t = (tid >= st) ? loc[tid - st] : 0;
        __syncthreads();
        loc[tid] += t;
        __syncthreads();
    }
    int excl = loc[tid] - v + beg;     // global CSR offset for node (b<<8)+tid
    int n = (b << 8) + tid;
    if (n < NN) off[n] = excl;
    __syncthreads();
    deg[tid] = excl;                   // reuse as cursor
    __syncthreads();
    for (int i = beg + tid; i < end; i += 256) {
        uint2 pr = pairs[i];
        int pos = atomicAdd(&deg[pr.y & 255], 1);
        srt[pos] = (int)pr.x;
    }
}

// ---------------------------------------------------------------------------
// Mean aggregation, CSR + chunked, ALL 4 chunk passes in one launch:
// p = blockIdx / AGG_GRID. In-order-ish dispatch keeps one 3.2MB slab L2-hot
// at a time (perf heuristic only). 4 lanes/node, uint2 gathers, unroll x4,
// natural node order (R7 perm regressed: srt locality > degree uniformity).
// NT output stores protect the slab from eviction.
// ---------------------------------------------------------------------------
static __device__ __forceinline__ void acc8(floatx2* ac, uint2 v) {
    ac[0] += __builtin_amdgcn_cvt_pk_f32_fp8((int)v.x, false);
    ac[1] += __builtin_amdgcn_cvt_pk_f32_fp8((int)v.x, true);
    ac[2] += __builtin_amdgcn_cvt_pk_f32_fp8((int)v.y, false);
    ac[3] += __builtin_amdgcn_cvt_pk_f32_fp8((int)v.y, true);
}

__global__ __launch_bounds__(256) void agg_csr(const uint* __restrict__ feat8,
                                               const int* __restrict__ srt,
                                               const int* __restrict__ off,
                                               ushort* __restrict__ aggb) {
    int bid = blockIdx.x;
    int p = bid / AGG_GRID;
    int n = (bid - p * AGG_GRID) * 64 + (threadIdx.x >> 2);
    int l = threadIdx.x & 3;
    if (n >= NN) return;
    const uint2* f = (const uint2*)(feat8 + (size_t)p * (NN * 8)) + l;

    int beg = off[n];
    int end = (n < NN - 1) ? off[n + 1] : NE;

    floatx2 ac[4];
    #pragma unroll
    for (int t = 0; t < 4; ++t) ac[t] = (floatx2){0.f, 0.f};

    int i = beg;
    for (; i + 4 <= end; i += 4) {
        int i0 = srt[i], i1 = srt[i + 1], i2 = srt[i + 2], i3 = srt[i + 3];
        uint2 v0 = f[(size_t)i0 * 4];
        uint2 v1 = f[(size_t)i1 * 4];
        uint2 v2 = f[(size_t)i2 * 4];
        uint2 v3 = f[(size_t)i3 * 4];
        acc8(ac, v0);
        acc8(ac, v1);
        acc8(ac, v2);
        acc8(ac, v3);
    }
    for (; i < end; ++i) {
        uint2 v = f[(size_t)srt[i] * 4];
        acc8(ac, v);
    }

    float inv = 1.0f / fmaxf((float)(end - beg), 1.0f);
    uintx4 o;
    o.x = (uint)f2bf(ac[0].x * inv) | ((uint)f2bf(ac[0].y * inv) << 16);
    o.y = (uint)f2bf(ac[1].x * inv) | ((uint)f2bf(ac[1].y * inv) << 16);
    o.z = (uint)f2bf(ac[2].x * inv) | ((uint)f2bf(ac[2].y * inv) << 16);
    o.w = (uint)f2bf(ac[3].x * inv) | ((uint)f2bf(ac[3].y * inv) << 16);
    uintx4* dp = (uintx4*)(aggb + (size_t)n * 128 + p * 32 + l * 8);
    __builtin_nontemporal_store(o, dp);
}

// ---------------------------------------------------------------------------
// Fused GEMM: C[n,j] = act( [agg|self][n,:] @ WT[j,:] + bias[j] ), K=256.
// 512 threads = 8 waves, 128 rows/block. WT staged in LDS (XOR swizzle, 64KB).
// F8OUT: also emit fp8 chunk-major (layer-2 agg input) -> conv_h eliminated.
// ---------------------------------------------------------------------------
template <int RELU, int BF16OUT, int F8OUT>
__global__ __launch_bounds__(512, 4) void gemm_mfma(
        const ushort* __restrict__ aggb, const ushort* __restrict__ selfb,
        const ushort* __restrict__ WT, const float* __restrict__ bias,
        void* __restrict__ outv, uchar* __restrict__ f8out) {
    __shared__ ushort sWT[128 * 256];            // 64KB, swizzled chunks
    const int tid = threadIdx.x;
    const int blk = blockIdx.x;

    #pragma unroll
    for (int it = 0; it < 8; ++it) {
        int flat = it * 512 + tid;               // 0..4095
        int col = flat >> 5;
        int c = flat & 31;
        uint4 v = *(const uint4*)(WT + (size_t)col * 256 + c * 8);
        *(uint4*)&sWT[col * 256 + (c ^ (col & 7)) * 8] = v;
    }

    const int w = tid >> 6;
    const int lane = tid & 63;
    const int m = lane & 15;
    const int q = lane >> 4;

    int node_m = blk * 128 + w * 16 + m;
    int cn = node_m < NN ? node_m : NN - 1;
    const ushort* arow = aggb + (size_t)cn * 128;
    const ushort* xrow = selfb + (size_t)cn * 128;
    short8 a[8];
    #pragma unroll
    for (int kk = 0; kk < 4; ++kk) {
        a[kk]     = *(const short8*)(arow + kk * 32 + q * 8);
        a[4 + kk] = *(const short8*)(xrow + kk * 32 + q * 8);
    }

    __syncthreads();

    floatx4 acc[8];
    #pragma unroll
    for (int t = 0; t < 8; ++t) acc[t] = (floatx4){0.f, 0.f, 0.f, 0.f};

    const int m7 = m & 7;
    #pragma unroll
    for (int kk = 0; kk < 8; ++kk) {
        int cx = (kk * 4 + q) ^ m7;
        #pragma unroll
        for (int t = 0; t < 8; ++t) {
            short8 b = *(const short8*)&sWT[(t * 16 + m) * 256 + cx * 8];
            acc[t] = __builtin_amdgcn_mfma_f32_16x16x32_bf16(a[kk], b, acc[t], 0, 0, 0);
        }
    }

    const int node_base = blk * 128 + w * 16 + q * 4;
    #pragma unroll
    for (int t = 0; t < 8; ++t) {
        int col = t * 16 + m;
        float bj = bias[col];
        #pragma unroll
        for (int r = 0; r < 4; ++r) {
            int node = node_base + r;
            if (node < NN) {
                float v = acc[t][r] + bj;
                if (RELU) v = fmaxf(v, 0.0f);
                if (BF16OUT)
                    ((ushort*)outv)[(size_t)node * 128 + col] = f2bf(v);
                else
                    ((float*)outv)[(size_t)node * 128 + col] = v;
                if (F8OUT) {
                    uint pk = (uint)__builtin_amdgcn_cvt_pk_fp8_f32(v, v, 0, false);
                    f8out[((size_t)(col >> 5) * NN + node) * 32 + (col & 31)] =
                        (uchar)pk;
                }
            }
        }
    }
}

// ---------------------------------------------------------------------------
extern "C" void kernel_launch(void* const* d_in, const int* in_sizes, int n_in,
                              void* d_out, int out_size, void* d_ws, size_t ws_size,
                              hipStream_t stream) {
    const float* x   = (const float*)d_in[0];
    const int*   ei  = (const int*)d_in[1];
    const float* W1l = (const float*)d_in[2];
    const float* b1  = (const float*)d_in[3];
    const float* W1r = (const float*)d_in[4];
    const float* W2l = (const float*)d_in[5];
    const float* b2  = (const float*)d_in[6];
    const float* W2r = (const float*)d_in[7];
    float*       out = (float*)d_out;

    const int* src = ei;
    const int* dst = ei + NE;

    // workspace layout (bytes), total 96.93 MB
    char* ws = (char*)d_ws;
    int*    off  = (int*)(ws);                   // 400000
    int*    srt  = (int*)(ws + 400000);          // 6400000 (ends 6.8MB)
    ushort* WT1  = (ushort*)(ws + 7200000);      // 65536
    ushort* WT2  = (ushort*)(ws + 7265536);      // 65536
    ushort* xb   = (ushort*)(ws + 7331072);      // 25600000
    uint*   xf8c = (uint*)(ws + 32931072);       // 12800000 (chunk-major fp8)
    ushort* aggb = (ushort*)(ws + 45731072);     // 25600000
    ushort* hb   = (ushort*)(ws + 71331072);     // 25600000 (end 96.93MB)
    uchar*  hf8c = (uchar*)xf8c;                 // alias: xf8c dead after agg L1
    // CSR-build temporaries, all dead before aggb is written:
    uint2*  pairs = (uint2*)aggb;                       // 12800000
    int*    gcnt  = (int*)((char*)aggb + 12800000);     // 1564
    int*    goff  = (int*)((char*)aggb + 12801600);     // 1568
    int*    gcur  = (int*)((char*)aggb + 12803200);     // 1564

    // ---- CSR build + input conversion ----
    (void)hipMemsetAsync(gcnt, 0, NBUCK * 4, stream);
    fused_pre<<<PA_BLOCKS + CX_BLOCKS + CW_BLOCKS, 256, 0, stream>>>(
        x, xb, xf8c, W1l, W1r, W2l, W2r, WT1, WT2, dst, gcnt);
    pS_scan<<<1, 512, 0, stream>>>(gcnt, goff, gcur);
    pB_part<<<PB_BLOCKS, 512, 0, stream>>>(src, dst, gcur, pairs);
    pC_scatter<<<NBUCK, 256, 0, stream>>>(pairs, goff, off, srt);

    const int gemm_grid = (NN + 127) / 128;

    // ---- layer 1 ----  (4 chunk passes in ONE launch; in-order dispatch
    //                     keeps each 3.2MB slab L2-hot)
    agg_csr<<<4 * AGG_GRID, 256, 0, stream>>>(xf8c, srt, off, aggb);
    gemm_mfma<1, 1, 1><<<gemm_grid, 512, 0, stream>>>(aggb, xb, WT1, b1, hb, hf8c);

    // ---- layer 2 ----
    agg_csr<<<4 * AGG_GRID, 256, 0, stream>>>((const uint*)hf8c, srt, off, aggb);
    gemm_mfma<0, 0, 0><<<gemm_grid, 512, 0, stream>>>(aggb, hb, WT2, b2, out, nullptr);
}

// Round 9
// 236.743 us; speedup vs baseline: 1.2165x; 1.0264x over previous
//
#include <hip/hip_runtime.h>

#define NN 100000
#define NE 1600000
#define DF 128
#define NBUCK 391      // ceil(NN/256); bucket b = dst >> 8
#define PA_BLOCKS 784  // ceil(NE / 2048), 8 edges/thread @256
#define PB_BLOCKS 391  // ceil(NE / 4096), 8 edges/thread @512
#define CX_BLOCKS 6250 // NN*DF/8 / 256
#define CW_BLOCKS 128
#define AGG_GRID 1568  // ceil(NN/64) padded to a multiple of 8: block i of every
                       // chunk pass lands on the same XCD -> srt/off L2-persistent

typedef short short8 __attribute__((ext_vector_type(8)));
typedef float floatx4 __attribute__((ext_vector_type(4)));
typedef float floatx2 __attribute__((ext_vector_type(2)));
typedef unsigned int uintx4 __attribute__((ext_vector_type(4)));
typedef unsigned int uint;
typedef unsigned short ushort;
typedef unsigned char uchar;

// float -> bf16 (RNE; inputs finite)
static __device__ __forceinline__ ushort f2bf(float f) {
    uint u = __builtin_bit_cast(uint, f);
    return (ushort)((u + 0x7fffu + ((u >> 16) & 1u)) >> 16);
}

// ---------------------------------------------------------------------------
// Fused pre-pass, block-range split; pA first (R8: fixed the straggler tail).
// ---------------------------------------------------------------------------
__global__ __launch_bounds__(256) void fused_pre(
        const float* __restrict__ x, ushort* __restrict__ xb, uint* __restrict__ xf8c,
        const float* __restrict__ W1l, const float* __restrict__ W1r,
        const float* __restrict__ W2l, const float* __restrict__ W2r,
        ushort* __restrict__ WT1, ushort* __restrict__ WT2,
        const int* __restrict__ dst, int* __restrict__ gcnt) {
    __shared__ int h[NBUCK];
    int bid = blockIdx.x;
    int tid = threadIdx.x;
    if (bid < PA_BLOCKS) {
        for (int i = tid; i < NBUCK; i += 256) h[i] = 0;
        __syncthreads();
        int eb = bid * 2048 + tid;
        #pragma unroll
        for (int k = 0; k < 8; ++k) {
            int e = eb + k * 256;
            if (e < NE) atomicAdd(&h[dst[e] >> 8], 1);
        }
        __syncthreads();
        for (int i = tid; i < NBUCK; i += 256)
            if (h[i]) atomicAdd(&gcnt[i], h[i]);
    } else if (bid < PA_BLOCKS + CX_BLOCKS) {
        int j = (bid - PA_BLOCKS) * 256 + tid;  // 0 .. NN*DF/8-1, slab-linear
        int p = j / (NN * 4);
        int rem = j - p * (NN * 4);
        int node = rem >> 2, q2 = rem & 3;
        const float4* xr = (const float4*)(x + (size_t)node * 128 + p * 32 + q2 * 8);
        float4 v0 = xr[0], v1 = xr[1];
        uint4 ob;
        ob.x = (uint)f2bf(v0.x) | ((uint)f2bf(v0.y) << 16);
        ob.y = (uint)f2bf(v0.z) | ((uint)f2bf(v0.w) << 16);
        ob.z = (uint)f2bf(v1.x) | ((uint)f2bf(v1.y) << 16);
        ob.w = (uint)f2bf(v1.z) | ((uint)f2bf(v1.w) << 16);
        *(uint4*)(xb + (size_t)node * 128 + p * 32 + q2 * 8) = ob;
        uint pk0 = (uint)__builtin_amdgcn_cvt_pk_fp8_f32(v0.x, v0.y, 0, false);
        pk0 = (uint)__builtin_amdgcn_cvt_pk_fp8_f32(v0.z, v0.w, (int)pk0, true);
        uint pk1 = (uint)__builtin_amdgcn_cvt_pk_fp8_f32(v1.x, v1.y, 0, false);
        pk1 = (uint)__builtin_amdgcn_cvt_pk_fp8_f32(v1.z, v1.w, (int)pk1, true);
        ((uint2*)xf8c)[j] = make_uint2(pk0, pk1);
    } else {
        int id = (bid - PA_BLOCKS - CX_BLOCKS) * 256 + tid;
        int n = id >> 8, k = id & 255;
        float a = (k < 128) ? W1l[k * 128 + n] : W1r[(k - 128) * 128 + n];
        float b = (k < 128) ? W2l[k * 128 + n] : W2r[(k - 128) * 128 + n];
        WT1[id] = f2bf(a);
        WT2[id] = f2bf(b);
    }
}

// Pass S: exclusive scan of bucket counts -> goff (bucket base in srt); gcur=goff.
__global__ __launch_bounds__(512) void pS_scan(const int* __restrict__ gcnt,
                                               int* __restrict__ goff,
                                               int* __restrict__ gcur) {
    __shared__ int s[512];
    int tid = threadIdx.x;
    int v = (tid < NBUCK) ? gcnt[tid] : 0;
    s[tid] = v;
    __syncthreads();
    for (int st = 1; st < 512; st <<= 1) {
        int t = (tid >= st) ? s[tid - st] : 0;
        __syncthreads();
        s[tid] += t;
        __syncthreads();
    }
    if (tid < NBUCK) {
        int e = s[tid] - v;
        goff[tid] = e;
        gcur[tid] = e;
    }
    if (tid == 0) goff[NBUCK] = NE;
}

// Pass B: partition (src,dst) pairs bucket-contiguous. Per-block LDS ranks;
// one global atomicAdd per (block,bucket). 8 edges/thread, 391 blocks.
__global__ __launch_bounds__(512) void pB_part(const int* __restrict__ src,
                                               const int* __restrict__ dst,
                                               int* __restrict__ gcur,
                                               uint2* __restrict__ pairs) {
    __shared__ int h[NBUCK];
    __shared__ int base[NBUCK];
    for (int i = threadIdx.x; i < NBUCK; i += 512) h[i] = 0;
    __syncthreads();
    int eb = blockIdx.x * 4096 + threadIdx.x;
    int bkt[8], dv[8];
    #pragma unroll
    for (int k = 0; k < 8; ++k) {
        int e = eb + k * 512;
        bkt[k] = -1;
        if (e < NE) {
            int d = dst[e];
            dv[k] = d;
            bkt[k] = d >> 8;
            atomicAdd(&h[bkt[k]], 1);
        }
    }
    __syncthreads();
    for (int i = threadIdx.x; i < NBUCK; i += 512) {
        base[i] = h[i] ? atomicAdd(&gcur[i], h[i]) : 0;
        h[i] = 0;
    }
    __syncthreads();
    #pragma unroll
    for (int k = 0; k < 8; ++k) {
        int e = eb + k * 512;
        if (e < NE) {
            int r = atomicAdd(&h[bkt[k]], 1);
            pairs[base[bkt[k]] + r] = make_uint2((uint)src[e], (uint)dv[k]);
        }
    }
}

// Pass C: one block per bucket. LDS degree count + scan -> off[] (coalesced),
// then scatter src into the bucket's ~16KB srt window (single-XCD dirtying,
// no write amplification). Second pairs read is L2-hot.
__global__ __launch_bounds__(256) void pC_scatter(const uint2* __restrict__ pairs,
                                                  const int* __restrict__ goff,
                                                  int* __restrict__ off,
                                                  int* __restrict__ srt) {
    __shared__ int deg[256];
    __shared__ int loc[256];
    int b = blockIdx.x;
    int beg = goff[b], end = goff[b + 1];
    int tid = threadIdx.x;
    deg[tid] = 0;
    __syncthreads();
    for (int i = beg + tid; i < end; i += 256)
        atomicAdd(&deg[pairs[i].y & 255], 1);
    __syncthreads();
    int v = deg[tid];
    loc[tid] = v;
    __syncthreads();
    for (int st = 1; st < 256; st <<= 1) {
        int t = (tid >= st) ? loc[tid - st] : 0;
        __syncthreads();
        loc[tid] += t;
        __syncthreads();
    }
    int excl = loc[tid] - v + beg;     // global CSR offset for node (b<<8)+tid
    int n = (b << 8) + tid;
    if (n < NN) off[n] = excl;
    __syncthreads();
    deg[tid] = excl;                   // reuse as cursor
    __syncthreads();
    for (int i = beg + tid; i < end; i += 256) {
        uint2 pr = pairs[i];
        int pos = atomicAdd(&deg[pr.y & 255], 1);
        srt[pos] = (int)pr.x;
    }
}

// ---------------------------------------------------------------------------
// Mean aggregation, CSR + chunked, 4 passes in one launch (p = bid/AGG_GRID).
// R8 counters: latency-bound (HBM 37%, VALU 28%, 0 conflicts; FETCH at floor).
// R9: (a) 8-deep gather pipeline (batch idx loads -> 8 independent gathers in
// flight, 2x MLP); (b) AGG_GRID%8==0 so srt/off segments stay L2-resident
// across passes. 4 lanes/node, uint2 gathers, NT output stores.
// ---------------------------------------------------------------------------
static __device__ __forceinline__ void acc8(floatx2* ac, uint2 v) {
    ac[0] += __builtin_amdgcn_cvt_pk_f32_fp8((int)v.x, false);
    ac[1] += __builtin_amdgcn_cvt_pk_f32_fp8((int)v.x, true);
    ac[2] += __builtin_amdgcn_cvt_pk_f32_fp8((int)v.y, false);
    ac[3] += __builtin_amdgcn_cvt_pk_f32_fp8((int)v.y, true);
}

__global__ __launch_bounds__(256) void agg_csr(const uint* __restrict__ feat8,
                                               const int* __restrict__ srt,
                                               const int* __restrict__ off,
                                               ushort* __restrict__ aggb) {
    int bid = blockIdx.x;
    int p = bid / AGG_GRID;
    int n = (bid - p * AGG_GRID) * 64 + (threadIdx.x >> 2);
    int l = threadIdx.x & 3;
    if (n >= NN) return;
    const uint2* f = (const uint2*)(feat8 + (size_t)p * (NN * 8)) + l;

    int beg = off[n];
    int end = (n < NN - 1) ? off[n + 1] : NE;

    floatx2 ac[4];
    #pragma unroll
    for (int t = 0; t < 4; ++t) ac[t] = (floatx2){0.f, 0.f};

    int i = beg;
    for (; i + 8 <= end; i += 8) {
        int idx[8];
        #pragma unroll
        for (int k = 0; k < 8; ++k) idx[k] = srt[i + k];
        uint2 v[8];
        #pragma unroll
        for (int k = 0; k < 8; ++k) v[k] = f[(size_t)idx[k] * 4];
        #pragma unroll
        for (int k = 0; k < 8; ++k) acc8(ac, v[k]);
    }
    if (i + 4 <= end) {
        int idx[4];
        #pragma unroll
        for (int k = 0; k < 4; ++k) idx[k] = srt[i + k];
        uint2 v[4];
        #pragma unroll
        for (int k = 0; k < 4; ++k) v[k] = f[(size_t)idx[k] * 4];
        #pragma unroll
        for (int k = 0; k < 4; ++k) acc8(ac, v[k]);
        i += 4;
    }
    for (; i < end; ++i) {
        uint2 v = f[(size_t)srt[i] * 4];
        acc8(ac, v);
    }

    float inv = 1.0f / fmaxf((float)(end - beg), 1.0f);
    uintx4 o;
    o.x = (uint)f2bf(ac[0].x * inv) | ((uint)f2bf(ac[0].y * inv) << 16);
    o.y = (uint)f2bf(ac[1].x * inv) | ((uint)f2bf(ac[1].y * inv) << 16);
    o.z = (uint)f2bf(ac[2].x * inv) | ((uint)f2bf(ac[2].y * inv) << 16);
    o.w = (uint)f2bf(ac[3].x * inv) | ((uint)f2bf(ac[3].y * inv) << 16);
    uintx4* dp = (uintx4*)(aggb + (size_t)n * 128 + p * 32 + l * 8);
    __builtin_nontemporal_store(o, dp);
}

// ---------------------------------------------------------------------------
// Fused GEMM: C[n,j] = act( [agg|self][n,:] @ WT[j,:] + bias[j] ), K=256.
// 512 threads = 8 waves, 128 rows/block. WT staged in LDS (XOR swizzle, 64KB).
// F8OUT: also emit fp8 chunk-major (layer-2 agg input) -> conv_h eliminated.
// ---------------------------------------------------------------------------
template <int RELU, int BF16OUT, int F8OUT>
__global__ __launch_bounds__(512, 4) void gemm_mfma(
        const ushort* __restrict__ aggb, const ushort* __restrict__ selfb,
        const ushort* __restrict__ WT, const float* __restrict__ bias,
        void* __restrict__ outv, uchar* __restrict__ f8out) {
    __shared__ ushort sWT[128 * 256];            // 64KB, swizzled chunks
    const int tid = threadIdx.x;
    const int blk = blockIdx.x;

    #pragma unroll
    for (int it = 0; it < 8; ++it) {
        int flat = it * 512 + tid;               // 0..4095
        int col = flat >> 5;
        int c = flat & 31;
        uint4 v = *(const uint4*)(WT + (size_t)col * 256 + c * 8);
        *(uint4*)&sWT[col * 256 + (c ^ (col & 7)) * 8] = v;
    }

    const int w = tid >> 6;
    const int lane = tid & 63;
    const int m = lane & 15;
    const int q = lane >> 4;

    int node_m = blk * 128 + w * 16 + m;
    int cn = node_m < NN ? node_m : NN - 1;
    const ushort* arow = aggb + (size_t)cn * 128;
    const ushort* xrow = selfb + (size_t)cn * 128;
    short8 a[8];
    #pragma unroll
    for (int kk = 0; kk < 4; ++kk) {
        a[kk]     = *(const short8*)(arow + kk * 32 + q * 8);
        a[4 + kk] = *(const short8*)(xrow + kk * 32 + q * 8);
    }

    __syncthreads();

    floatx4 acc[8];
    #pragma unroll
    for (int t = 0; t < 8; ++t) acc[t] = (floatx4){0.f, 0.f, 0.f, 0.f};

    const int m7 = m & 7;
    #pragma unroll
    for (int kk = 0; kk < 8; ++kk) {
        int cx = (kk * 4 + q) ^ m7;
        #pragma unroll
        for (int t = 0; t < 8; ++t) {
            short8 b = *(const short8*)&sWT[(t * 16 + m) * 256 + cx * 8];
            acc[t] = __builtin_amdgcn_mfma_f32_16x16x32_bf16(a[kk], b, acc[t], 0, 0, 0);
        }
    }

    const int node_base = blk * 128 + w * 16 + q * 4;
    #pragma unroll
    for (int t = 0; t < 8; ++t) {
        int col = t * 16 + m;
        float bj = bias[col];
        #pragma unroll
        for (int r = 0; r < 4; ++r) {
            int node = node_base + r;
            if (node < NN) {
                float v = acc[t][r] + bj;
                if (RELU) v = fmaxf(v, 0.0f);
                if (BF16OUT)
                    ((ushort*)outv)[(size_t)node * 128 + col] = f2bf(v);
                else
                    ((float*)outv)[(size_t)node * 128 + col] = v;
                if (F8OUT) {
                    uint pk = (uint)__builtin_amdgcn_cvt_pk_fp8_f32(v, v, 0, false);
                    f8out[((size_t)(col >> 5) * NN + node) * 32 + (col & 31)] =
                        (uchar)pk;
                }
            }
        }
    }
}

// ---------------------------------------------------------------------------
extern "C" void kernel_launch(void* const* d_in, const int* in_sizes, int n_in,
                              void* d_out, int out_size, void* d_ws, size_t ws_size,
                              hipStream_t stream) {
    const float* x   = (const float*)d_in[0];
    const int*   ei  = (const int*)d_in[1];
    const float* W1l = (const float*)d_in[2];
    const float* b1  = (const float*)d_in[3];
    const float* W1r = (const float*)d_in[4];
    const float* W2l = (const float*)d_in[5];
    const float* b2  = (const float*)d_in[6];
    const float* W2r = (const float*)d_in[7];
    float*       out = (float*)d_out;

    const int* src = ei;
    const int* dst = ei + NE;

    // workspace layout (bytes), total 96.93 MB
    char* ws = (char*)d_ws;
    int*    off  = (int*)(ws);                   // 400000
    int*    srt  = (int*)(ws + 400000);          // 6400000 (ends 6.8MB)
    ushort* WT1  = (ushort*)(ws + 7200000);      // 65536
    ushort* WT2  = (ushort*)(ws + 7265536);      // 65536
    ushort* xb   = (ushort*)(ws + 7331072);      // 25600000
    uint*   xf8c = (uint*)(ws + 32931072);       // 12800000 (chunk-major fp8)
    ushort* aggb = (ushort*)(ws + 45731072);     // 25600000
    ushort* hb   = (ushort*)(ws + 71331072);     // 25600000 (end 96.93MB)
    uchar*  hf8c = (uchar*)xf8c;                 // alias: xf8c dead after agg L1
    // CSR-build temporaries, all dead before aggb is written:
    uint2*  pairs = (uint2*)aggb;                       // 12800000
    int*    gcnt  = (int*)((char*)aggb + 12800000);     // 1564
    int*    goff  = (int*)((char*)aggb + 12801600);     // 1568
    int*    gcur  = (int*)((char*)aggb + 12803200);     // 1564

    // ---- CSR build + input conversion ----
    (void)hipMemsetAsync(gcnt, 0, NBUCK * 4, stream);
    fused_pre<<<PA_BLOCKS + CX_BLOCKS + CW_BLOCKS, 256, 0, stream>>>(
        x, xb, xf8c, W1l, W1r, W2l, W2r, WT1, WT2, dst, gcnt);
    pS_scan<<<1, 512, 0, stream>>>(gcnt, goff, gcur);
    pB_part<<<PB_BLOCKS, 512, 0, stream>>>(src, dst, gcur, pairs);
    pC_scatter<<<NBUCK, 256, 0, stream>>>(pairs, goff, off, srt);

    const int gemm_grid = (NN + 127) / 128;

    // ---- layer 1 ----  (4 chunk passes in ONE launch; block i -> same XCD
    //                     every pass, so srt/off stay L2-hot)
    agg_csr<<<4 * AGG_GRID, 256, 0, stream>>>(xf8c, srt, off, aggb);
    gemm_mfma<1, 1, 1><<<gemm_grid, 512, 0, stream>>>(aggb, xb, WT1, b1, hb, hf8c);

    // ---- layer 2 ----
    agg_csr<<<4 * AGG_GRID, 256, 0, stream>>>((const uint*)hf8c, srt, off, aggb);
    gemm_mfma<0, 0, 0><<<gemm_grid, 512, 0, stream>>>(aggb, hb, WT2, b2, out, nullptr);
}

// Round 10
// 223.768 us; speedup vs baseline: 1.2871x; 1.0580x over previous
//
#include <hip/hip_runtime.h>

#define NN 100000
#define NE 1600000
#define DF 128
#define NBUCK 391      // ceil(NN/256); bucket b = dst >> 8
#define PA_BLOCKS 784  // ceil(NE / 2048), 8 edges/thread @256
#define PB_BLOCKS 391  // ceil(NE / 4096), 8 edges/thread @512
#define CX_BLOCKS 3125 // NN*DF/8 / 512
#define CW_BLOCKS 64   // 128*256 / 512
#define AGG_GRID 1568  // ceil(NN/64) padded to %8==0: stable block->XCD mapping

typedef short short8 __attribute__((ext_vector_type(8)));
typedef float floatx4 __attribute__((ext_vector_type(4)));
typedef float floatx2 __attribute__((ext_vector_type(2)));
typedef unsigned int uintx4 __attribute__((ext_vector_type(4)));
typedef unsigned int uint;
typedef unsigned short ushort;
typedef unsigned char uchar;

// float -> bf16 (RNE; inputs finite)
static __device__ __forceinline__ ushort f2bf(float f) {
    uint u = __builtin_bit_cast(uint, f);
    return (ushort)((u + 0x7fffu + ((u >> 16) & 1u)) >> 16);
}

// ---------------------------------------------------------------------------
// pA: bucket histogram (LDS-aggregated). Standalone so pS can run while the
// heavy conv_x work is deferred into fused_mid (overlapped with pB).
// ---------------------------------------------------------------------------
__global__ __launch_bounds__(256) void pA_hist(const int* __restrict__ dst,
                                               int* __restrict__ gcnt) {
    __shared__ int h[NBUCK];
    int tid = threadIdx.x;
    for (int i = tid; i < NBUCK; i += 256) h[i] = 0;
    __syncthreads();
    int eb = blockIdx.x * 2048 + tid;
    #pragma unroll
    for (int k = 0; k < 8; ++k) {
        int e = eb + k * 256;
        if (e < NE) atomicAdd(&h[dst[e] >> 8], 1);
    }
    __syncthreads();
    for (int i = tid; i < NBUCK; i += 256)
        if (h[i]) atomicAdd(&gcnt[i], h[i]);
}

// Pass S: exclusive scan of bucket counts -> goff (bucket base in srt); gcur=goff.
__global__ __launch_bounds__(512) void pS_scan(const int* __restrict__ gcnt,
                                               int* __restrict__ goff,
                                               int* __restrict__ gcur) {
    __shared__ int s[512];
    int tid = threadIdx.x;
    int v = (tid < NBUCK) ? gcnt[tid] : 0;
    s[tid] = v;
    __syncthreads();
    for (int st = 1; st < 512; st <<= 1) {
        int t = (tid >= st) ? s[tid - st] : 0;
        __syncthreads();
        s[tid] += t;
        __syncthreads();
    }
    if (tid < NBUCK) {
        int e = s[tid] - v;
        goff[tid] = e;
        gcur[tid] = e;
    }
    if (tid == 0) goff[NBUCK] = NE;
}

// ---------------------------------------------------------------------------
// fused_mid: pB (bucket partition) overlapped with conv_x + conv_w.
//   [0, PB)           pB: partition (src,dst) bucket-contiguous
//   [PB, PB+CX)       conv_x: x fp32 -> xb bf16 + xf8c fp8 slab-linear
//   [PB+CX, +CW)      conv_w: W^T bf16 build
// ---------------------------------------------------------------------------
__global__ __launch_bounds__(512) void fused_mid(
        const int* __restrict__ src, const int* __restrict__ dst,
        int* __restrict__ gcur, uint2* __restrict__ pairs,
        const float* __restrict__ x, ushort* __restrict__ xb, uint* __restrict__ xf8c,
        const float* __restrict__ W1l, const float* __restrict__ W1r,
        const float* __restrict__ W2l, const float* __restrict__ W2r,
        ushort* __restrict__ WT1, ushort* __restrict__ WT2) {
    __shared__ int h[NBUCK];
    __shared__ int base[NBUCK];
    int bid = blockIdx.x;
    int tid = threadIdx.x;
    if (bid < PB_BLOCKS) {
        for (int i = tid; i < NBUCK; i += 512) h[i] = 0;
        __syncthreads();
        int eb = bid * 4096 + tid;
        int bkt[8], dv[8];
        #pragma unroll
        for (int k = 0; k < 8; ++k) {
            int e = eb + k * 512;
            bkt[k] = -1;
            if (e < NE) {
                int d = dst[e];
                dv[k] = d;
                bkt[k] = d >> 8;
                atomicAdd(&h[bkt[k]], 1);
            }
        }
        __syncthreads();
        for (int i = tid; i < NBUCK; i += 512) {
            base[i] = h[i] ? atomicAdd(&gcur[i], h[i]) : 0;
            h[i] = 0;
        }
        __syncthreads();
        #pragma unroll
        for (int k = 0; k < 8; ++k) {
            int e = eb + k * 512;
            if (e < NE) {
                int r = atomicAdd(&h[bkt[k]], 1);
                pairs[base[bkt[k]] + r] = make_uint2((uint)src[e], (uint)dv[k]);
            }
        }
    } else if (bid < PB_BLOCKS + CX_BLOCKS) {
        int j = (bid - PB_BLOCKS) * 512 + tid;  // 0 .. NN*DF/8-1, slab-linear
        int p = j / (NN * 4);
        int rem = j - p * (NN * 4);
        int node = rem >> 2, q2 = rem & 3;
        const float4* xr = (const float4*)(x + (size_t)node * 128 + p * 32 + q2 * 8);
        float4 v0 = xr[0], v1 = xr[1];
        uint4 ob;
        ob.x = (uint)f2bf(v0.x) | ((uint)f2bf(v0.y) << 16);
        ob.y = (uint)f2bf(v0.z) | ((uint)f2bf(v0.w) << 16);
        ob.z = (uint)f2bf(v1.x) | ((uint)f2bf(v1.y) << 16);
        ob.w = (uint)f2bf(v1.z) | ((uint)f2bf(v1.w) << 16);
        *(uint4*)(xb + (size_t)node * 128 + p * 32 + q2 * 8) = ob;
        uint pk0 = (uint)__builtin_amdgcn_cvt_pk_fp8_f32(v0.x, v0.y, 0, false);
        pk0 = (uint)__builtin_amdgcn_cvt_pk_fp8_f32(v0.z, v0.w, (int)pk0, true);
        uint pk1 = (uint)__builtin_amdgcn_cvt_pk_fp8_f32(v1.x, v1.y, 0, false);
        pk1 = (uint)__builtin_amdgcn_cvt_pk_fp8_f32(v1.z, v1.w, (int)pk1, true);
        ((uint2*)xf8c)[j] = make_uint2(pk0, pk1);
    } else {
        int id = (bid - PB_BLOCKS - CX_BLOCKS) * 512 + tid;
        int n = id >> 8, k = id & 255;
        float a = (k < 128) ? W1l[k * 128 + n] : W1r[(k - 128) * 128 + n];
        float b = (k < 128) ? W2l[k * 128 + n] : W2r[(k - 128) * 128 + n];
        WT1[id] = f2bf(a);
        WT2[id] = f2bf(b);
    }
}

// Pass C: one block per bucket. LDS degree count + scan -> off[] (coalesced),
// then scatter src into the bucket's ~16KB srt window (single-XCD dirtying,
// no write amplification). Second pairs read is L2-hot.
__global__ __launch_bounds__(256) void pC_scatter(const uint2* __restrict__ pairs,
                                                  const int* __restrict__ goff,
                                                  int* __restrict__ off,
                                                  int* __restrict__ srt) {
    __shared__ int deg[256];
    __shared__ int loc[256];
    int b = blockIdx.x;
    int beg = goff[b], end = goff[b + 1];
    int tid = threadIdx.x;
    deg[tid] = 0;
    __syncthreads();
    for (int i = beg + tid; i < end; i += 256)
        atomicAdd(&deg[pairs[i].y & 255], 1);
    __syncthreads();
    int v = deg[tid];
    loc[tid] = v;
    __syncthreads();
    for (int st = 1; st < 256; st <<= 1) {
        int t = (tid >= st) ? loc[tid - st] : 0;
        __syncthreads();
        loc[tid] += t;
        __syncthreads();
    }
    int excl = loc[tid] - v + beg;     // global CSR offset for node (b<<8)+tid
    int n = (b << 8) + tid;
    if (n < NN) off[n] = excl;
    __syncthreads();
    deg[tid] = excl;                   // reuse as cursor
    __syncthreads();
    for (int i = beg + tid; i < end; i += 256) {
        uint2 pr = pairs[i];
        int pos = atomicAdd(&deg[pr.y & 255], 1);
        srt[pos] = (int)pr.x;
    }
}

// ---------------------------------------------------------------------------
// Mean aggregation, CSR + chunked, 4 passes/launch. R9 counters: exposed
// latency on the srt(L2)->gather(L2) dependent chain. R10: the block's 64
// nodes own a CONTIGUOUS srt segment (~1024 entries) -> stage it in LDS once;
// index loads become ds_read (~40cy) instead of L2 (~200cy). Overflow >2048
// (>mu+32sigma, effectively never) falls back to global per node.
// ---------------------------------------------------------------------------
static __device__ __forceinline__ void acc8(floatx2* ac, uint2 v) {
    ac[0] += __builtin_amdgcn_cvt_pk_f32_fp8((int)v.x, false);
    ac[1] += __builtin_amdgcn_cvt_pk_f32_fp8((int)v.x, true);
    ac[2] += __builtin_amdgcn_cvt_pk_f32_fp8((int)v.y, false);
    ac[3] += __builtin_amdgcn_cvt_pk_f32_fp8((int)v.y, true);
}

#define AGG_LOOP(IDX)                                            \
    {                                                            \
        int i = lb;                                              \
        for (; i + 8 <= le; i += 8) {                            \
            int idx[8];                                          \
            _Pragma("unroll")                                    \
            for (int k = 0; k < 8; ++k) idx[k] = IDX(i + k);     \
            uint2 v[8];                                          \
            _Pragma("unroll")                                    \
            for (int k = 0; k < 8; ++k) v[k] = f[(size_t)idx[k] * 4]; \
            _Pragma("unroll")                                    \
            for (int k = 0; k < 8; ++k) acc8(ac, v[k]);          \
        }                                                        \
        if (i + 4 <= le) {                                       \
            int idx[4];                                          \
            _Pragma("unroll")                                    \
            for (int k = 0; k < 4; ++k) idx[k] = IDX(i + k);     \
            uint2 v[4];                                          \
            _Pragma("unroll")                                    \
            for (int k = 0; k < 4; ++k) v[k] = f[(size_t)idx[k] * 4]; \
            _Pragma("unroll")                                    \
            for (int k = 0; k < 4; ++k) acc8(ac, v[k]);          \
            i += 4;                                              \
        }                                                        \
        for (; i < le; ++i) {                                    \
            uint2 v = f[(size_t)IDX(i) * 4];                     \
            acc8(ac, v);                                         \
        }                                                        \
    }

__global__ __launch_bounds__(256) void agg_csr(const uint* __restrict__ feat8,
                                               const int* __restrict__ srt,
                                               const int* __restrict__ off,
                                               ushort* __restrict__ aggb) {
    __shared__ int sidx[2048];
    int bid = blockIdx.x;
    int p = bid / AGG_GRID;
    int nb = (bid - p * AGG_GRID) * 64;
    if (nb >= NN) return;                        // uniform per block
    int tid = threadIdx.x;

    int segb = off[nb];
    int nend = nb + 64;
    int sege = (nend < NN) ? off[nend] : NE;
    int stage = min(sege - segb, 2048);
    for (int i = tid; i < stage; i += 256) sidx[i] = srt[segb + i];
    __syncthreads();

    int n = nb + (tid >> 2);
    int l = tid & 3;
    if (n >= NN) return;
    const uint2* f = (const uint2*)(feat8 + (size_t)p * (NN * 8)) + l;

    int beg = off[n];
    int end = (n < NN - 1) ? off[n + 1] : NE;
    int lb = beg - segb, le = end - segb;

    floatx2 ac[4];
    #pragma unroll
    for (int t = 0; t < 4; ++t) ac[t] = (floatx2){0.f, 0.f};

    if (le <= stage) {
        #define IDX_LDS(ii) sidx[ii]
        AGG_LOOP(IDX_LDS)
        #undef IDX_LDS
    } else {
        #define IDX_GBL(ii) srt[segb + (ii)]
        AGG_LOOP(IDX_GBL)
        #undef IDX_GBL
    }

    float inv = 1.0f / fmaxf((float)(end - beg), 1.0f);
    uintx4 o;
    o.x = (uint)f2bf(ac[0].x * inv) | ((uint)f2bf(ac[0].y * inv) << 16);
    o.y = (uint)f2bf(ac[1].x * inv) | ((uint)f2bf(ac[1].y * inv) << 16);
    o.z = (uint)f2bf(ac[2].x * inv) | ((uint)f2bf(ac[2].y * inv) << 16);
    o.w = (uint)f2bf(ac[3].x * inv) | ((uint)f2bf(ac[3].y * inv) << 16);
    uintx4* dp = (uintx4*)(aggb + (size_t)n * 128 + p * 32 + l * 8);
    __builtin_nontemporal_store(o, dp);
}

// ---------------------------------------------------------------------------
// Fused GEMM: C[n,j] = act( [agg|self][n,:] @ WT[j,:] + bias[j] ), K=256.
// 512 threads = 8 waves, 128 rows/block. WT staged in LDS (XOR swizzle, 64KB).
// F8OUT: also emit fp8 chunk-major (layer-2 agg input) -> conv_h eliminated.
// ---------------------------------------------------------------------------
template <int RELU, int BF16OUT, int F8OUT>
__global__ __launch_bounds__(512, 4) void gemm_mfma(
        const ushort* __restrict__ aggb, const ushort* __restrict__ selfb,
        const ushort* __restrict__ WT, const float* __restrict__ bias,
        void* __restrict__ outv, uchar* __restrict__ f8out) {
    __shared__ ushort sWT[128 * 256];            // 64KB, swizzled chunks
    const int tid = threadIdx.x;
    const int blk = blockIdx.x;

    #pragma unroll
    for (int it = 0; it < 8; ++it) {
        int flat = it * 512 + tid;               // 0..4095
        int col = flat >> 5;
        int c = flat & 31;
        uint4 v = *(const uint4*)(WT + (size_t)col * 256 + c * 8);
        *(uint4*)&sWT[col * 256 + (c ^ (col & 7)) * 8] = v;
    }

    const int w = tid >> 6;
    const int lane = tid & 63;
    const int m = lane & 15;
    const int q = lane >> 4;

    int node_m = blk * 128 + w * 16 + m;
    int cn = node_m < NN ? node_m : NN - 1;
    const ushort* arow = aggb + (size_t)cn * 128;
    const ushort* xrow = selfb + (size_t)cn * 128;
    short8 a[8];
    #pragma unroll
    for (int kk = 0; kk < 4; ++kk) {
        a[kk]     = *(const short8*)(arow + kk * 32 + q * 8);
        a[4 + kk] = *(const short8*)(xrow + kk * 32 + q * 8);
    }

    __syncthreads();

    floatx4 acc[8];
    #pragma unroll
    for (int t = 0; t < 8; ++t) acc[t] = (floatx4){0.f, 0.f, 0.f, 0.f};

    const int m7 = m & 7;
    #pragma unroll
    for (int kk = 0; kk < 8; ++kk) {
        int cx = (kk * 4 + q) ^ m7;
        #pragma unroll
        for (int t = 0; t < 8; ++t) {
            short8 b = *(const short8*)&sWT[(t * 16 + m) * 256 + cx * 8];
            acc[t] = __builtin_amdgcn_mfma_f32_16x16x32_bf16(a[kk], b, acc[t], 0, 0, 0);
        }
    }

    const int node_base = blk * 128 + w * 16 + q * 4;
    #pragma unroll
    for (int t = 0; t < 8; ++t) {
        int col = t * 16 + m;
        float bj = bias[col];
        #pragma unroll
        for (int r = 0; r < 4; ++r) {
            int node = node_base + r;
            if (node < NN) {
                float v = acc[t][r] + bj;
                if (RELU) v = fmaxf(v, 0.0f);
                if (BF16OUT)
                    ((ushort*)outv)[(size_t)node * 128 + col] = f2bf(v);
                else
                    ((float*)outv)[(size_t)node * 128 + col] = v;
                if (F8OUT) {
                    uint pk = (uint)__builtin_amdgcn_cvt_pk_fp8_f32(v, v, 0, false);
                    f8out[((size_t)(col >> 5) * NN + node) * 32 + (col & 31)] =
                        (uchar)pk;
                }
            }
        }
    }
}

// ---------------------------------------------------------------------------
extern "C" void kernel_launch(void* const* d_in, const int* in_sizes, int n_in,
                              void* d_out, int out_size, void* d_ws, size_t ws_size,
                              hipStream_t stream) {
    const float* x   = (const float*)d_in[0];
    const int*   ei  = (const int*)d_in[1];
    const float* W1l = (const float*)d_in[2];
    const float* b1  = (const float*)d_in[3];
    const float* W1r = (const float*)d_in[4];
    const float* W2l = (const float*)d_in[5];
    const float* b2  = (const float*)d_in[6];
    const float* W2r = (const float*)d_in[7];
    float*       out = (float*)d_out;

    const int* src = ei;
    const int* dst = ei + NE;

    // workspace layout (bytes), total 96.93 MB
    char* ws = (char*)d_ws;
    int*    off  = (int*)(ws);                   // 400000
    int*    srt  = (int*)(ws + 400000);          // 6400000 (ends 6.8MB)
    ushort* WT1  = (ushort*)(ws + 7200000);      // 65536
    ushort* WT2  = (ushort*)(ws + 7265536);      // 65536
    ushort* xb   = (ushort*)(ws + 7331072);      // 25600000
    uint*   xf8c = (uint*)(ws + 32931072);       // 12800000 (chunk-major fp8)
    ushort* aggb = (ushort*)(ws + 45731072);     // 25600000
    ushort* hb   = (ushort*)(ws + 71331072);     // 25600000 (end 96.93MB)
    uchar*  hf8c = (uchar*)xf8c;                 // alias: xf8c dead after agg L1
    // CSR-build temporaries, all dead before aggb is written:
    uint2*  pairs = (uint2*)aggb;                       // 12800000
    int*    gcnt  = (int*)((char*)aggb + 12800000);     // 1564
    int*    goff  = (int*)((char*)aggb + 12801600);     // 1568
    int*    gcur  = (int*)((char*)aggb + 12803200);     // 1564

    // ---- CSR build + input conversion (pB overlapped with conv_x/conv_w) ----
    (void)hipMemsetAsync(gcnt, 0, NBUCK * 4, stream);
    pA_hist<<<PA_BLOCKS, 256, 0, stream>>>(dst, gcnt);
    pS_scan<<<1, 512, 0, stream>>>(gcnt, goff, gcur);
    fused_mid<<<PB_BLOCKS + CX_BLOCKS + CW_BLOCKS, 512, 0, stream>>>(
        src, dst, gcur, pairs, x, xb, xf8c, W1l, W1r, W2l, W2r, WT1, WT2);
    pC_scatter<<<NBUCK, 256, 0, stream>>>(pairs, goff, off, srt);

    const int gemm_grid = (NN + 127) / 128;

    // ---- layer 1 ----  (4 chunk passes in ONE launch; block i -> same XCD
    //                     every pass, so srt/off stay L2-hot)
    agg_csr<<<4 * AGG_GRID, 256, 0, stream>>>(xf8c, srt, off, aggb);
    gemm_mfma<1, 1, 1><<<gemm_grid, 512, 0, stream>>>(aggb, xb, WT1, b1, hb, hf8c);

    // ---- layer 2 ----
    agg_csr<<<4 * AGG_GRID, 256, 0, stream>>>((const uint*)hf8c, srt, off, aggb);
    gemm_mfma<0, 0, 0><<<gemm_grid, 512, 0, stream>>>(aggb, hb, WT2, b2, out, nullptr);
}

// Round 11
// 195.181 us; speedup vs baseline: 1.4756x; 1.1465x over previous
//
#include <hip/hip_runtime.h>

#define NN 100000
#define NE 1600000
#define DF 128
#define NBUCK 391      // ceil(NN/256); bucket b = dst >> 8
#define PA_BLOCKS 784  // ceil(NE / 2048), 8 edges/thread @256
#define PB_BLOCKS 391  // ceil(NE / 4096), 8 edges/thread @512
#define CX_BLOCKS 3125 // NN*DF/8 / 512
#define CW_BLOCKS 64   // 128*256 / 512
#define AGG_GRID 3128  // ceil(NN/32) padded to %8==0: stable block->XCD mapping

typedef short short8 __attribute__((ext_vector_type(8)));
typedef float floatx4 __attribute__((ext_vector_type(4)));
typedef float floatx2 __attribute__((ext_vector_type(2)));
typedef unsigned int uintx4 __attribute__((ext_vector_type(4)));
typedef unsigned int uint;
typedef unsigned short ushort;
typedef unsigned char uchar;

// float -> bf16 (RNE; inputs finite)
static __device__ __forceinline__ ushort f2bf(float f) {
    uint u = __builtin_bit_cast(uint, f);
    return (ushort)((u + 0x7fffu + ((u >> 16) & 1u)) >> 16);
}

// ---------------------------------------------------------------------------
// pA: bucket histogram (LDS-aggregated).
// ---------------------------------------------------------------------------
__global__ __launch_bounds__(256) void pA_hist(const int* __restrict__ dst,
                                               int* __restrict__ gcnt) {
    __shared__ int h[NBUCK];
    int tid = threadIdx.x;
    for (int i = tid; i < NBUCK; i += 256) h[i] = 0;
    __syncthreads();
    int eb = blockIdx.x * 2048 + tid;
    #pragma unroll
    for (int k = 0; k < 8; ++k) {
        int e = eb + k * 256;
        if (e < NE) atomicAdd(&h[dst[e] >> 8], 1);
    }
    __syncthreads();
    for (int i = tid; i < NBUCK; i += 256)
        if (h[i]) atomicAdd(&gcnt[i], h[i]);
}

// Pass S: exclusive scan of bucket counts -> goff (bucket base in srt); gcur=goff.
__global__ __launch_bounds__(512) void pS_scan(const int* __restrict__ gcnt,
                                               int* __restrict__ goff,
                                               int* __restrict__ gcur) {
    __shared__ int s[512];
    int tid = threadIdx.x;
    int v = (tid < NBUCK) ? gcnt[tid] : 0;
    s[tid] = v;
    __syncthreads();
    for (int st = 1; st < 512; st <<= 1) {
        int t = (tid >= st) ? s[tid - st] : 0;
        __syncthreads();
        s[tid] += t;
        __syncthreads();
    }
    if (tid < NBUCK) {
        int e = s[tid] - v;
        goff[tid] = e;
        gcur[tid] = e;
    }
    if (tid == 0) goff[NBUCK] = NE;
}

// ---------------------------------------------------------------------------
// fused_mid: pB (bucket partition) overlapped with conv_x + conv_w.
// conv_x now fully LINEAR (xf8 row-major; single-pass agg needs no slabs).
// ---------------------------------------------------------------------------
__global__ __launch_bounds__(512) void fused_mid(
        const int* __restrict__ src, const int* __restrict__ dst,
        int* __restrict__ gcur, uint2* __restrict__ pairs,
        const float* __restrict__ x, ushort* __restrict__ xb, uint* __restrict__ xf8,
        const float* __restrict__ W1l, const float* __restrict__ W1r,
        const float* __restrict__ W2l, const float* __restrict__ W2r,
        ushort* __restrict__ WT1, ushort* __restrict__ WT2) {
    __shared__ int h[NBUCK];
    __shared__ int base[NBUCK];
    int bid = blockIdx.x;
    int tid = threadIdx.x;
    if (bid < PB_BLOCKS) {
        for (int i = tid; i < NBUCK; i += 512) h[i] = 0;
        __syncthreads();
        int eb = bid * 4096 + tid;
        int bkt[8], dv[8];
        #pragma unroll
        for (int k = 0; k < 8; ++k) {
            int e = eb + k * 512;
            bkt[k] = -1;
            if (e < NE) {
                int d = dst[e];
                dv[k] = d;
                bkt[k] = d >> 8;
                atomicAdd(&h[bkt[k]], 1);
            }
        }
        __syncthreads();
        for (int i = tid; i < NBUCK; i += 512) {
            base[i] = h[i] ? atomicAdd(&gcur[i], h[i]) : 0;
            h[i] = 0;
        }
        __syncthreads();
        #pragma unroll
        for (int k = 0; k < 8; ++k) {
            int e = eb + k * 512;
            if (e < NE) {
                int r = atomicAdd(&h[bkt[k]], 1);
                pairs[base[bkt[k]] + r] = make_uint2((uint)src[e], (uint)dv[k]);
            }
        }
    } else if (bid < PB_BLOCKS + CX_BLOCKS) {
        int j = (bid - PB_BLOCKS) * 512 + tid;   // elem group [j*8, j*8+8)
        const float4* xr = (const float4*)x + (size_t)j * 2;
        float4 v0 = xr[0], v1 = xr[1];
        uint4 ob;
        ob.x = (uint)f2bf(v0.x) | ((uint)f2bf(v0.y) << 16);
        ob.y = (uint)f2bf(v0.z) | ((uint)f2bf(v0.w) << 16);
        ob.z = (uint)f2bf(v1.x) | ((uint)f2bf(v1.y) << 16);
        ob.w = (uint)f2bf(v1.z) | ((uint)f2bf(v1.w) << 16);
        ((uint4*)xb)[j] = ob;
        uint pk0 = (uint)__builtin_amdgcn_cvt_pk_fp8_f32(v0.x, v0.y, 0, false);
        pk0 = (uint)__builtin_amdgcn_cvt_pk_fp8_f32(v0.z, v0.w, (int)pk0, true);
        uint pk1 = (uint)__builtin_amdgcn_cvt_pk_fp8_f32(v1.x, v1.y, 0, false);
        pk1 = (uint)__builtin_amdgcn_cvt_pk_fp8_f32(v1.z, v1.w, (int)pk1, true);
        ((uint2*)xf8)[j] = make_uint2(pk0, pk1);
    } else {
        int id = (bid - PB_BLOCKS - CX_BLOCKS) * 512 + tid;
        int n = id >> 8, k = id & 255;
        float a = (k < 128) ? W1l[k * 128 + n] : W1r[(k - 128) * 128 + n];
        float b = (k < 128) ? W2l[k * 128 + n] : W2r[(k - 128) * 128 + n];
        WT1[id] = f2bf(a);
        WT2[id] = f2bf(b);
    }
}

// Pass C: one block per bucket. LDS degree count + scan -> off[] (coalesced),
// then scatter src into the bucket's ~16KB srt window.
__global__ __launch_bounds__(256) void pC_scatter(const uint2* __restrict__ pairs,
                                                  const int* __restrict__ goff,
                                                  int* __restrict__ off,
                                                  int* __restrict__ srt) {
    __shared__ int deg[256];
    __shared__ int loc[256];
    int b = blockIdx.x;
    int beg = goff[b], end = goff[b + 1];
    int tid = threadIdx.x;
    deg[tid] = 0;
    __syncthreads();
    for (int i = beg + tid; i < end; i += 256)
        atomicAdd(&deg[pairs[i].y & 255], 1);
    __syncthreads();
    int v = deg[tid];
    loc[tid] = v;
    __syncthreads();
    for (int st = 1; st < 256; st <<= 1) {
        int t = (tid >= st) ? loc[tid - st] : 0;
        __syncthreads();
        loc[tid] += t;
        __syncthreads();
    }
    int excl = loc[tid] - v + beg;     // global CSR offset for node (b<<8)+tid
    int n = (b << 8) + tid;
    if (n < NN) off[n] = excl;
    __syncthreads();
    deg[tid] = excl;                   // reuse as cursor
    __syncthreads();
    for (int i = beg + tid; i < end; i += 256) {
        uint2 pr = pairs[i];
        int pos = atomicAdd(&deg[pr.y & 255], 1);
        srt[pos] = (int)pr.x;
    }
}

// ---------------------------------------------------------------------------
// Mean aggregation, SINGLE PASS over row-major fp8 (R11): each edge visited
// once (was 4x). 8 lanes/node x uint4 = full 128B row per edge, all lines
// fully used. 32 nodes/block; srt segment (~512 entries) LDS-staged once;
// 8-deep independent gather batches; NT bf16 output (256B/node row).
// Working set 12.8MB: L3-resident (R10 FETCH proved L3 absorbs slab misses).
// ---------------------------------------------------------------------------
static __device__ __forceinline__ void acc16(floatx2* ac, uint4 v) {
    ac[0] += __builtin_amdgcn_cvt_pk_f32_fp8((int)v.x, false);
    ac[1] += __builtin_amdgcn_cvt_pk_f32_fp8((int)v.x, true);
    ac[2] += __builtin_amdgcn_cvt_pk_f32_fp8((int)v.y, false);
    ac[3] += __builtin_amdgcn_cvt_pk_f32_fp8((int)v.y, true);
    ac[4] += __builtin_amdgcn_cvt_pk_f32_fp8((int)v.z, false);
    ac[5] += __builtin_amdgcn_cvt_pk_f32_fp8((int)v.z, true);
    ac[6] += __builtin_amdgcn_cvt_pk_f32_fp8((int)v.w, false);
    ac[7] += __builtin_amdgcn_cvt_pk_f32_fp8((int)v.w, true);
}

#define AGG_LOOP(IDX)                                            \
    {                                                            \
        int i = lb;                                              \
        for (; i + 8 <= le; i += 8) {                            \
            int idx[8];                                          \
            _Pragma("unroll")                                    \
            for (int k = 0; k < 8; ++k) idx[k] = IDX(i + k);     \
            uint4 v[8];                                          \
            _Pragma("unroll")                                    \
            for (int k = 0; k < 8; ++k) v[k] = f[(size_t)idx[k] * 8]; \
            _Pragma("unroll")                                    \
            for (int k = 0; k < 8; ++k) acc16(ac, v[k]);         \
        }                                                        \
        if (i + 4 <= le) {                                       \
            int idx[4];                                          \
            _Pragma("unroll")                                    \
            for (int k = 0; k < 4; ++k) idx[k] = IDX(i + k);     \
            uint4 v[4];                                          \
            _Pragma("unroll")                                    \
            for (int k = 0; k < 4; ++k) v[k] = f[(size_t)idx[k] * 8]; \
            _Pragma("unroll")                                    \
            for (int k = 0; k < 4; ++k) acc16(ac, v[k]);         \
            i += 4;                                              \
        }                                                        \
        for (; i < le; ++i) {                                    \
            uint4 v = f[(size_t)IDX(i) * 8];                     \
            acc16(ac, v);                                        \
        }                                                        \
    }

__global__ __launch_bounds__(256) void agg_csr(const uint* __restrict__ feat8,
                                               const int* __restrict__ srt,
                                               const int* __restrict__ off,
                                               ushort* __restrict__ aggb) {
    __shared__ int sidx[2048];
    int nb = blockIdx.x * 32;
    if (nb >= NN) return;                        // uniform per block
    int tid = threadIdx.x;

    int segb = off[nb];
    int nend = nb + 32;
    int sege = (nend < NN) ? off[nend] : NE;
    int stage = min(sege - segb, 2048);
    for (int i = tid; i < stage; i += 256) sidx[i] = srt[segb + i];
    __syncthreads();

    int n = nb + (tid >> 3);
    int l = tid & 7;
    if (n >= NN) return;
    const uint4* f = (const uint4*)feat8 + l;    // row stride = 8 uint4 (128B)

    int beg = off[n];
    int end = (n < NN - 1) ? off[n + 1] : NE;
    int lb = beg - segb, le = end - segb;

    floatx2 ac[8];
    #pragma unroll
    for (int t = 0; t < 8; ++t) ac[t] = (floatx2){0.f, 0.f};

    if (le <= stage) {
        #define IDX_LDS(ii) sidx[ii]
        AGG_LOOP(IDX_LDS)
        #undef IDX_LDS
    } else {
        #define IDX_GBL(ii) srt[segb + (ii)]
        AGG_LOOP(IDX_GBL)
        #undef IDX_GBL
    }

    float inv = 1.0f / fmaxf((float)(end - beg), 1.0f);
    uintx4 o0, o1;
    o0.x = (uint)f2bf(ac[0].x * inv) | ((uint)f2bf(ac[0].y * inv) << 16);
    o0.y = (uint)f2bf(ac[1].x * inv) | ((uint)f2bf(ac[1].y * inv) << 16);
    o0.z = (uint)f2bf(ac[2].x * inv) | ((uint)f2bf(ac[2].y * inv) << 16);
    o0.w = (uint)f2bf(ac[3].x * inv) | ((uint)f2bf(ac[3].y * inv) << 16);
    o1.x = (uint)f2bf(ac[4].x * inv) | ((uint)f2bf(ac[4].y * inv) << 16);
    o1.y = (uint)f2bf(ac[5].x * inv) | ((uint)f2bf(ac[5].y * inv) << 16);
    o1.z = (uint)f2bf(ac[6].x * inv) | ((uint)f2bf(ac[6].y * inv) << 16);
    o1.w = (uint)f2bf(ac[7].x * inv) | ((uint)f2bf(ac[7].y * inv) << 16);
    uintx4* dp = (uintx4*)(aggb + (size_t)n * 128 + l * 16);
    __builtin_nontemporal_store(o0, dp);
    __builtin_nontemporal_store(o1, dp + 1);
}

// ---------------------------------------------------------------------------
// Fused GEMM: C[n,j] = act( [agg|self][n,:] @ WT[j,:] + bias[j] ), K=256.
// 512 threads = 8 waves, 128 rows/block. WT staged in LDS (XOR swizzle, 64KB).
// F8OUT: emit fp8 ROW-MAJOR (single-pass agg input) -> contiguous epilogue.
// ---------------------------------------------------------------------------
template <int RELU, int BF16OUT, int F8OUT>
__global__ __launch_bounds__(512, 4) void gemm_mfma(
        const ushort* __restrict__ aggb, const ushort* __restrict__ selfb,
        const ushort* __restrict__ WT, const float* __restrict__ bias,
        void* __restrict__ outv, uchar* __restrict__ f8out) {
    __shared__ ushort sWT[128 * 256];            // 64KB, swizzled chunks
    const int tid = threadIdx.x;
    const int blk = blockIdx.x;

    #pragma unroll
    for (int it = 0; it < 8; ++it) {
        int flat = it * 512 + tid;               // 0..4095
        int col = flat >> 5;
        int c = flat & 31;
        uint4 v = *(const uint4*)(WT + (size_t)col * 256 + c * 8);
        *(uint4*)&sWT[col * 256 + (c ^ (col & 7)) * 8] = v;
    }

    const int w = tid >> 6;
    const int lane = tid & 63;
    const int m = lane & 15;
    const int q = lane >> 4;

    int node_m = blk * 128 + w * 16 + m;
    int cn = node_m < NN ? node_m : NN - 1;
    const ushort* arow = aggb + (size_t)cn * 128;
    const ushort* xrow = selfb + (size_t)cn * 128;
    short8 a[8];
    #pragma unroll
    for (int kk = 0; kk < 4; ++kk) {
        a[kk]     = *(const short8*)(arow + kk * 32 + q * 8);
        a[4 + kk] = *(const short8*)(xrow + kk * 32 + q * 8);
    }

    __syncthreads();

    floatx4 acc[8];
    #pragma unroll
    for (int t = 0; t < 8; ++t) acc[t] = (floatx4){0.f, 0.f, 0.f, 0.f};

    const int m7 = m & 7;
    #pragma unroll
    for (int kk = 0; kk < 8; ++kk) {
        int cx = (kk * 4 + q) ^ m7;
        #pragma unroll
        for (int t = 0; t < 8; ++t) {
            short8 b = *(const short8*)&sWT[(t * 16 + m) * 256 + cx * 8];
            acc[t] = __builtin_amdgcn_mfma_f32_16x16x32_bf16(a[kk], b, acc[t], 0, 0, 0);
        }
    }

    const int node_base = blk * 128 + w * 16 + q * 4;
    #pragma unroll
    for (int t = 0; t < 8; ++t) {
        int col = t * 16 + m;
        float bj = bias[col];
        #pragma unroll
        for (int r = 0; r < 4; ++r) {
            int node = node_base + r;
            if (node < NN) {
                float v = acc[t][r] + bj;
                if (RELU) v = fmaxf(v, 0.0f);
                if (BF16OUT)
                    ((ushort*)outv)[(size_t)node * 128 + col] = f2bf(v);
                else
                    ((float*)outv)[(size_t)node * 128 + col] = v;
                if (F8OUT) {
                    uint pk = (uint)__builtin_amdgcn_cvt_pk_fp8_f32(v, v, 0, false);
                    f8out[(size_t)node * 128 + col] = (uchar)pk;
                }
            }
        }
    }
}

// ---------------------------------------------------------------------------
extern "C" void kernel_launch(void* const* d_in, const int* in_sizes, int n_in,
                              void* d_out, int out_size, void* d_ws, size_t ws_size,
                              hipStream_t stream) {
    const float* x   = (const float*)d_in[0];
    const int*   ei  = (const int*)d_in[1];
    const float* W1l = (const float*)d_in[2];
    const float* b1  = (const float*)d_in[3];
    const float* W1r = (const float*)d_in[4];
    const float* W2l = (const float*)d_in[5];
    const float* b2  = (const float*)d_in[6];
    const float* W2r = (const float*)d_in[7];
    float*       out = (float*)d_out;

    const int* src = ei;
    const int* dst = ei + NE;

    // workspace layout (bytes), total 96.93 MB
    char* ws = (char*)d_ws;
    int*    off  = (int*)(ws);                   // 400000
    int*    srt  = (int*)(ws + 400000);          // 6400000 (ends 6.8MB)
    ushort* WT1  = (ushort*)(ws + 7200000);      // 65536
    ushort* WT2  = (ushort*)(ws + 7265536);      // 65536
    ushort* xb   = (ushort*)(ws + 7331072);      // 25600000
    uint*   xf8  = (uint*)(ws + 32931072);       // 12800000 (row-major fp8)
    ushort* aggb = (ushort*)(ws + 45731072);     // 25600000
    ushort* hb   = (ushort*)(ws + 71331072);     // 25600000 (end 96.93MB)
    uchar*  hf8  = (uchar*)xf8;                  // alias: xf8 dead after agg L1
    // CSR-build temporaries, all dead before aggb is written:
    uint2*  pairs = (uint2*)aggb;                       // 12800000
    int*    gcnt  = (int*)((char*)aggb + 12800000);     // 1564
    int*    goff  = (int*)((char*)aggb + 12801600);     // 1568
    int*    gcur  = (int*)((char*)aggb + 12803200);     // 1564

    // ---- CSR build + input conversion (pB overlapped with conv_x/conv_w) ----
    (void)hipMemsetAsync(gcnt, 0, NBUCK * 4, stream);
    pA_hist<<<PA_BLOCKS, 256, 0, stream>>>(dst, gcnt);
    pS_scan<<<1, 512, 0, stream>>>(gcnt, goff, gcur);
    fused_mid<<<PB_BLOCKS + CX_BLOCKS + CW_BLOCKS, 512, 0, stream>>>(
        src, dst, gcur, pairs, x, xb, xf8, W1l, W1r, W2l, W2r, WT1, WT2);
    pC_scatter<<<NBUCK, 256, 0, stream>>>(pairs, goff, off, srt);

    const int gemm_grid = (NN + 127) / 128;

    // ---- layer 1 ----  (single-pass agg: every edge row gathered once)
    agg_csr<<<AGG_GRID, 256, 0, stream>>>(xf8, srt, off, aggb);
    gemm_mfma<1, 1, 1><<<gemm_grid, 512, 0, stream>>>(aggb, xb, WT1, b1, hb, hf8);

    // ---- layer 2 ----
    agg_csr<<<AGG_GRID, 256, 0, stream>>>((const uint*)hf8, srt, off, aggb);
    gemm_mfma<0, 0, 0><<<gemm_grid, 512, 0, stream>>>(aggb, hb, WT2, b2, out, nullptr);
}

// Round 12
// 183.660 us; speedup vs baseline: 1.5681x; 1.0627x over previous
//
#include <hip/hip_runtime.h>

#define NN 100000
#define NE 1600000
#define DF 128
#define NBUCK 391      // ceil(NN/256); bucket b = dst >> 8
#define PA_BLOCKS 784  // ceil(NE / 2048), 8 edges/thread @256
#define PB_BLOCKS 391  // ceil(NE / 4096), 8 edges/thread @512
#define CX_BLOCKS 3125 // NN*DF/8 / 512
#define CW_BLOCKS 64   // 128*256 / 512
#define AGG_GRID 3128  // ceil(NN/32) padded to %8==0: stable block->XCD mapping

typedef short short8 __attribute__((ext_vector_type(8)));
typedef float floatx4 __attribute__((ext_vector_type(4)));
typedef float floatx2 __attribute__((ext_vector_type(2)));
typedef unsigned int uintx4 __attribute__((ext_vector_type(4)));
typedef unsigned int uint;
typedef unsigned short ushort;
typedef unsigned char uchar;

// float -> bf16 (RNE; inputs finite)
static __device__ __forceinline__ ushort f2bf(float f) {
    uint u = __builtin_bit_cast(uint, f);
    return (ushort)((u + 0x7fffu + ((u >> 16) & 1u)) >> 16);
}

// ---------------------------------------------------------------------------
// ATOMIC-FREE CSR build (R12). R11 counters: fused_mid 46us at 4.5% VALU /
// <30% BW -> pB's 153K hot-line global atomicAdds (gcur reservation) were the
// serializer. Now offsets are deterministic:
//   pA: LDS histogram; STORE per-edge rank (the atomicAdd return) + per-block
//       hist row. Coalesced writes, no global atomics.
//   pS2: per-bucket column scan of hist (in place -> rel) + totals gt.
//   pS:  scan gt -> goff.
//   pB:  pos = goff[b] + rel[e>>11][b] + rank[e]. Pure loads + one store.
// ---------------------------------------------------------------------------
__global__ __launch_bounds__(256) void pA_hist(const int* __restrict__ dst,
                                               int* __restrict__ hist,
                                               ushort* __restrict__ rank8) {
    __shared__ int h[NBUCK];
    int tid = threadIdx.x;
    for (int i = tid; i < NBUCK; i += 256) h[i] = 0;
    __syncthreads();
    int eb = blockIdx.x * 2048 + tid;
    #pragma unroll
    for (int k = 0; k < 8; ++k) {
        int e = eb + k * 256;
        if (e < NE) {
            int r = atomicAdd(&h[dst[e] >> 8], 1);
            rank8[e] = (ushort)r;               // rank within (block,bucket)
        }
    }
    __syncthreads();
    int* hrow = hist + blockIdx.x * NBUCK;
    for (int i = tid; i < NBUCK; i += 256) hrow[i] = h[i];
}

// Per-bucket exclusive scan over blocks: hist[blk][b] -> rel (in place),
// column total -> gt[b]. One block per bucket; hist is 1.2MB L2-resident.
__global__ __launch_bounds__(256) void pS2_colscan(int* __restrict__ hist,
                                                   int* __restrict__ gt) {
    __shared__ int ps[256];
    int b = blockIdx.x;
    int tid = threadIdx.x;
    int v[4];
    int sum = 0;
    #pragma unroll
    for (int k = 0; k < 4; ++k) {
        int blk = tid * 4 + k;
        v[k] = (blk < PA_BLOCKS) ? hist[blk * NBUCK + b] : 0;
        sum += v[k];
    }
    ps[tid] = sum;
    __syncthreads();
    for (int st = 1; st < 256; st <<= 1) {
        int t = (tid >= st) ? ps[tid - st] : 0;
        __syncthreads();
        ps[tid] += t;
        __syncthreads();
    }
    int excl = ps[tid] - sum;
    #pragma unroll
    for (int k = 0; k < 4; ++k) {
        int blk = tid * 4 + k;
        if (blk < PA_BLOCKS) hist[blk * NBUCK + b] = excl;
        excl += v[k];
    }
    if (tid == 255) gt[b] = excl;               // column total
}

// Pass S: exclusive scan of bucket totals -> goff.
__global__ __launch_bounds__(512) void pS_scan(const int* __restrict__ gt,
                                               int* __restrict__ goff) {
    __shared__ int s[512];
    int tid = threadIdx.x;
    int v = (tid < NBUCK) ? gt[tid] : 0;
    s[tid] = v;
    __syncthreads();
    for (int st = 1; st < 512; st <<= 1) {
        int t = (tid >= st) ? s[tid - st] : 0;
        __syncthreads();
        s[tid] += t;
        __syncthreads();
    }
    if (tid < NBUCK) goff[tid] = s[tid] - v;
    if (tid == 0) goff[NBUCK] = NE;
}

// ---------------------------------------------------------------------------
// fused_mid: pB (deterministic scatter) overlapped with conv_x + conv_w.
// ---------------------------------------------------------------------------
__global__ __launch_bounds__(512) void fused_mid(
        const int* __restrict__ src, const int* __restrict__ dst,
        const ushort* __restrict__ rank8, const int* __restrict__ rel,
        const int* __restrict__ goff, uint2* __restrict__ pairs,
        const float* __restrict__ x, ushort* __restrict__ xb, uint* __restrict__ xf8,
        const float* __restrict__ W1l, const float* __restrict__ W1r,
        const float* __restrict__ W2l, const float* __restrict__ W2r,
        ushort* __restrict__ WT1, ushort* __restrict__ WT2) {
    int bid = blockIdx.x;
    int tid = threadIdx.x;
    if (bid < PB_BLOCKS) {
        int eb = bid * 4096 + tid;
        #pragma unroll
        for (int k = 0; k < 8; ++k) {
            int e = eb + k * 512;
            if (e < NE) {
                int s = src[e];
                int d = dst[e];
                int b = d >> 8;
                int pos = goff[b] + rel[(e >> 11) * NBUCK + b] + (int)rank8[e];
                pairs[pos] = make_uint2((uint)s, (uint)d);
            }
        }
    } else if (bid < PB_BLOCKS + CX_BLOCKS) {
        int j = (bid - PB_BLOCKS) * 512 + tid;   // elem group [j*8, j*8+8)
        const float4* xr = (const float4*)x + (size_t)j * 2;
        float4 v0 = xr[0], v1 = xr[1];
        uint4 ob;
        ob.x = (uint)f2bf(v0.x) | ((uint)f2bf(v0.y) << 16);
        ob.y = (uint)f2bf(v0.z) | ((uint)f2bf(v0.w) << 16);
        ob.z = (uint)f2bf(v1.x) | ((uint)f2bf(v1.y) << 16);
        ob.w = (uint)f2bf(v1.z) | ((uint)f2bf(v1.w) << 16);
        ((uint4*)xb)[j] = ob;
        uint pk0 = (uint)__builtin_amdgcn_cvt_pk_fp8_f32(v0.x, v0.y, 0, false);
        pk0 = (uint)__builtin_amdgcn_cvt_pk_fp8_f32(v0.z, v0.w, (int)pk0, true);
        uint pk1 = (uint)__builtin_amdgcn_cvt_pk_fp8_f32(v1.x, v1.y, 0, false);
        pk1 = (uint)__builtin_amdgcn_cvt_pk_fp8_f32(v1.z, v1.w, (int)pk1, true);
        ((uint2*)xf8)[j] = make_uint2(pk0, pk1);
    } else {
        int id = (bid - PB_BLOCKS - CX_BLOCKS) * 512 + tid;
        int n = id >> 8, k = id & 255;
        float a = (k < 128) ? W1l[k * 128 + n] : W1r[(k - 128) * 128 + n];
        float b = (k < 128) ? W2l[k * 128 + n] : W2r[(k - 128) * 128 + n];
        WT1[id] = f2bf(a);
        WT2[id] = f2bf(b);
    }
}

// Pass C: one block per bucket. LDS degree count + scan -> off[] (coalesced),
// then scatter src into the bucket's ~16KB srt window.
__global__ __launch_bounds__(256) void pC_scatter(const uint2* __restrict__ pairs,
                                                  const int* __restrict__ goff,
                                                  int* __restrict__ off,
                                                  int* __restrict__ srt) {
    __shared__ int deg[256];
    __shared__ int loc[256];
    int b = blockIdx.x;
    int beg = goff[b], end = goff[b + 1];
    int tid = threadIdx.x;
    deg[tid] = 0;
    __syncthreads();
    for (int i = beg + tid; i < end; i += 256)
        atomicAdd(&deg[pairs[i].y & 255], 1);
    __syncthreads();
    int v = deg[tid];
    loc[tid] = v;
    __syncthreads();
    for (int st = 1; st < 256; st <<= 1) {
        int t = (tid >= st) ? loc[tid - st] : 0;
        __syncthreads();
        loc[tid] += t;
        __syncthreads();
    }
    int excl = loc[tid] - v + beg;     // global CSR offset for node (b<<8)+tid
    int n = (b << 8) + tid;
    if (n < NN) off[n] = excl;
    __syncthreads();
    deg[tid] = excl;                   // reuse as cursor
    __syncthreads();
    for (int i = beg + tid; i < end; i += 256) {
        uint2 pr = pairs[i];
        int pos = atomicAdd(&deg[pr.y & 255], 1);
        srt[pos] = (int)pr.x;
    }
}

// ---------------------------------------------------------------------------
// Mean aggregation, SINGLE PASS over row-major fp8 (R11 design, unchanged).
// ---------------------------------------------------------------------------
static __device__ __forceinline__ void acc16(floatx2* ac, uint4 v) {
    ac[0] += __builtin_amdgcn_cvt_pk_f32_fp8((int)v.x, false);
    ac[1] += __builtin_amdgcn_cvt_pk_f32_fp8((int)v.x, true);
    ac[2] += __builtin_amdgcn_cvt_pk_f32_fp8((int)v.y, false);
    ac[3] += __builtin_amdgcn_cvt_pk_f32_fp8((int)v.y, true);
    ac[4] += __builtin_amdgcn_cvt_pk_f32_fp8((int)v.z, false);
    ac[5] += __builtin_amdgcn_cvt_pk_f32_fp8((int)v.z, true);
    ac[6] += __builtin_amdgcn_cvt_pk_f32_fp8((int)v.w, false);
    ac[7] += __builtin_amdgcn_cvt_pk_f32_fp8((int)v.w, true);
}

#define AGG_LOOP(IDX)                                            \
    {                                                            \
        int i = lb;                                              \
        for (; i + 8 <= le; i += 8) {                            \
            int idx[8];                                          \
            _Pragma("unroll")                                    \
            for (int k = 0; k < 8; ++k) idx[k] = IDX(i + k);     \
            uint4 v[8];                                          \
            _Pragma("unroll")                                    \
            for (int k = 0; k < 8; ++k) v[k] = f[(size_t)idx[k] * 8]; \
            _Pragma("unroll")                                    \
            for (int k = 0; k < 8; ++k) acc16(ac, v[k]);         \
        }                                                        \
        if (i + 4 <= le) {                                       \
            int idx[4];                                          \
            _Pragma("unroll")                                    \
            for (int k = 0; k < 4; ++k) idx[k] = IDX(i + k);     \
            uint4 v[4];                                          \
            _Pragma("unroll")                                    \
            for (int k = 0; k < 4; ++k) v[k] = f[(size_t)idx[k] * 8]; \
            _Pragma("unroll")                                    \
            for (int k = 0; k < 4; ++k) acc16(ac, v[k]);         \
            i += 4;                                              \
        }                                                        \
        for (; i < le; ++i) {                                    \
            uint4 v = f[(size_t)IDX(i) * 8];                     \
            acc16(ac, v);                                        \
        }                                                        \
    }

__global__ __launch_bounds__(256) void agg_csr(const uint* __restrict__ feat8,
                                               const int* __restrict__ srt,
                                               const int* __restrict__ off,
                                               ushort* __restrict__ aggb) {
    __shared__ int sidx[2048];
    int nb = blockIdx.x * 32;
    if (nb >= NN) return;                        // uniform per block
    int tid = threadIdx.x;

    int segb = off[nb];
    int nend = nb + 32;
    int sege = (nend < NN) ? off[nend] : NE;
    int stage = min(sege - segb, 2048);
    for (int i = tid; i < stage; i += 256) sidx[i] = srt[segb + i];
    __syncthreads();

    int n = nb + (tid >> 3);
    int l = tid & 7;
    if (n >= NN) return;
    const uint4* f = (const uint4*)feat8 + l;    // row stride = 8 uint4 (128B)

    int beg = off[n];
    int end = (n < NN - 1) ? off[n + 1] : NE;
    int lb = beg - segb, le = end - segb;

    floatx2 ac[8];
    #pragma unroll
    for (int t = 0; t < 8; ++t) ac[t] = (floatx2){0.f, 0.f};

    if (le <= stage) {
        #define IDX_LDS(ii) sidx[ii]
        AGG_LOOP(IDX_LDS)
        #undef IDX_LDS
    } else {
        #define IDX_GBL(ii) srt[segb + (ii)]
        AGG_LOOP(IDX_GBL)
        #undef IDX_GBL
    }

    float inv = 1.0f / fmaxf((float)(end - beg), 1.0f);
    uintx4 o0, o1;
    o0.x = (uint)f2bf(ac[0].x * inv) | ((uint)f2bf(ac[0].y * inv) << 16);
    o0.y = (uint)f2bf(ac[1].x * inv) | ((uint)f2bf(ac[1].y * inv) << 16);
    o0.z = (uint)f2bf(ac[2].x * inv) | ((uint)f2bf(ac[2].y * inv) << 16);
    o0.w = (uint)f2bf(ac[3].x * inv) | ((uint)f2bf(ac[3].y * inv) << 16);
    o1.x = (uint)f2bf(ac[4].x * inv) | ((uint)f2bf(ac[4].y * inv) << 16);
    o1.y = (uint)f2bf(ac[5].x * inv) | ((uint)f2bf(ac[5].y * inv) << 16);
    o1.z = (uint)f2bf(ac[6].x * inv) | ((uint)f2bf(ac[6].y * inv) << 16);
    o1.w = (uint)f2bf(ac[7].x * inv) | ((uint)f2bf(ac[7].y * inv) << 16);
    uintx4* dp = (uintx4*)(aggb + (size_t)n * 128 + l * 16);
    __builtin_nontemporal_store(o0, dp);
    __builtin_nontemporal_store(o1, dp + 1);
}

// ---------------------------------------------------------------------------
// Fused GEMM: C[n,j] = act( [agg|self][n,:] @ WT[j,:] + bias[j] ), K=256.
// 512 threads = 8 waves, 128 rows/block. WT staged in LDS (XOR swizzle, 64KB).
// F8OUT: emit fp8 ROW-MAJOR (single-pass agg input) -> contiguous epilogue.
// ---------------------------------------------------------------------------
template <int RELU, int BF16OUT, int F8OUT>
__global__ __launch_bounds__(512, 4) void gemm_mfma(
        const ushort* __restrict__ aggb, const ushort* __restrict__ selfb,
        const ushort* __restrict__ WT, const float* __restrict__ bias,
        void* __restrict__ outv, uchar* __restrict__ f8out) {
    __shared__ ushort sWT[128 * 256];            // 64KB, swizzled chunks
    const int tid = threadIdx.x;
    const int blk = blockIdx.x;

    #pragma unroll
    for (int it = 0; it < 8; ++it) {
        int flat = it * 512 + tid;               // 0..4095
        int col = flat >> 5;
        int c = flat & 31;
        uint4 v = *(const uint4*)(WT + (size_t)col * 256 + c * 8);
        *(uint4*)&sWT[col * 256 + (c ^ (col & 7)) * 8] = v;
    }

    const int w = tid >> 6;
    const int lane = tid & 63;
    const int m = lane & 15;
    const int q = lane >> 4;

    int node_m = blk * 128 + w * 16 + m;
    int cn = node_m < NN ? node_m : NN - 1;
    const ushort* arow = aggb + (size_t)cn * 128;
    const ushort* xrow = selfb + (size_t)cn * 128;
    short8 a[8];
    #pragma unroll
    for (int kk = 0; kk < 4; ++kk) {
        a[kk]     = *(const short8*)(arow + kk * 32 + q * 8);
        a[4 + kk] = *(const short8*)(xrow + kk * 32 + q * 8);
    }

    __syncthreads();

    floatx4 acc[8];
    #pragma unroll
    for (int t = 0; t < 8; ++t) acc[t] = (floatx4){0.f, 0.f, 0.f, 0.f};

    const int m7 = m & 7;
    #pragma unroll
    for (int kk = 0; kk < 8; ++kk) {
        int cx = (kk * 4 + q) ^ m7;
        #pragma unroll
        for (int t = 0; t < 8; ++t) {
            short8 b = *(const short8*)&sWT[(t * 16 + m) * 256 + cx * 8];
            acc[t] = __builtin_amdgcn_mfma_f32_16x16x32_bf16(a[kk], b, acc[t], 0, 0, 0);
        }
    }

    const int node_base = blk * 128 + w * 16 + q * 4;
    #pragma unroll
    for (int t = 0; t < 8; ++t) {
        int col = t * 16 + m;
        float bj = bias[col];
        #pragma unroll
        for (int r = 0; r < 4; ++r) {
            int node = node_base + r;
            if (node < NN) {
                float v = acc[t][r] + bj;
                if (RELU) v = fmaxf(v, 0.0f);
                if (BF16OUT)
                    ((ushort*)outv)[(size_t)node * 128 + col] = f2bf(v);
                else
                    ((float*)outv)[(size_t)node * 128 + col] = v;
                if (F8OUT) {
                    uint pk = (uint)__builtin_amdgcn_cvt_pk_fp8_f32(v, v, 0, false);
                    f8out[(size_t)node * 128 + col] = (uchar)pk;
                }
            }
        }
    }
}

// ---------------------------------------------------------------------------
extern "C" void kernel_launch(void* const* d_in, const int* in_sizes, int n_in,
                              void* d_out, int out_size, void* d_ws, size_t ws_size,
                              hipStream_t stream) {
    const float* x   = (const float*)d_in[0];
    const int*   ei  = (const int*)d_in[1];
    const float* W1l = (const float*)d_in[2];
    const float* b1  = (const float*)d_in[3];
    const float* W1r = (const float*)d_in[4];
    const float* W2l = (const float*)d_in[5];
    const float* b2  = (const float*)d_in[6];
    const float* W2r = (const float*)d_in[7];
    float*       out = (float*)d_out;

    const int* src = ei;
    const int* dst = ei + NE;

    // workspace layout (bytes), total 96.93 MB
    char* ws = (char*)d_ws;
    int*    off  = (int*)(ws);                   // 400000
    int*    srt  = (int*)(ws + 400000);          // 6400000 (ends 6.8MB)
    ushort* WT1  = (ushort*)(ws + 7200000);      // 65536
    ushort* WT2  = (ushort*)(ws + 7265536);      // 65536
    ushort* xb   = (ushort*)(ws + 7331072);      // 25600000
    uint*   xf8  = (uint*)(ws + 32931072);       // 12800000 (row-major fp8)
    ushort* aggb = (ushort*)(ws + 45731072);     // 25600000
    ushort* hb   = (ushort*)(ws + 71331072);     // 25600000 (end 96.93MB)
    uchar*  hf8  = (uchar*)xf8;                  // alias: xf8 dead after agg L1
    // CSR-build temporaries (alias aggb region, all dead before agg writes it):
    uint2*  pairs = (uint2*)aggb;                        // 12800000
    int*    hist  = (int*)((char*)aggb + 12800000);      // 784*391*4 = 1226176
    ushort* rank8 = (ushort*)((char*)aggb + 14100000);   // 3200000
    int*    gt    = (int*)((char*)aggb + 17300000);      // 1564
    int*    goff  = (int*)((char*)aggb + 17302000);      // 1568

    // ---- CSR build (atomic-free) + input conversion ----
    pA_hist<<<PA_BLOCKS, 256, 0, stream>>>(dst, hist, rank8);
    pS2_colscan<<<NBUCK, 256, 0, stream>>>(hist, gt);
    pS_scan<<<1, 512, 0, stream>>>(gt, goff);
    fused_mid<<<PB_BLOCKS + CX_BLOCKS + CW_BLOCKS, 512, 0, stream>>>(
        src, dst, rank8, hist, goff, pairs, x, xb, xf8,
        W1l, W1r, W2l, W2r, WT1, WT2);
    pC_scatter<<<NBUCK, 256, 0, stream>>>(pairs, goff, off, srt);

    const int gemm_grid = (NN + 127) / 128;

    // ---- layer 1 ----  (single-pass agg: every edge row gathered once)
    agg_csr<<<AGG_GRID, 256, 0, stream>>>(xf8, srt, off, aggb);
    gemm_mfma<1, 1, 1><<<gemm_grid, 512, 0, stream>>>(aggb, xb, WT1, b1, hb, hf8);

    // ---- layer 2 ----
    agg_csr<<<AGG_GRID, 256, 0, stream>>>((const uint*)hf8, srt, off, aggb);
    gemm_mfma<0, 0, 0><<<gemm_grid, 512, 0, stream>>>(aggb, hb, WT2, b2, out, nullptr);
}

// Round 13
// 181.789 us; speedup vs baseline: 1.5843x; 1.0103x over previous
//
#include <hip/hip_runtime.h>

#define NN 100000
#define NE 1600000
#define DF 128
#define NBUCK 391      // ceil(NN/256); bucket b = dst >> 8
#define PA_BLOCKS 196  // ceil(NE / 8192), 32 edges/thread @256
#define PB_BLOCKS 196  // ceil(NE / 8192), 16 edges/thread @512
#define CX_BLOCKS 3125 // NN*DF/8 / 512
#define CW_BLOCKS 64   // 128*256 / 512
#define AGG_GRID 3128  // ceil(NN/32) padded to %8==0

typedef short short8 __attribute__((ext_vector_type(8)));
typedef float floatx4 __attribute__((ext_vector_type(4)));
typedef float floatx2 __attribute__((ext_vector_type(2)));
typedef unsigned int uintx4 __attribute__((ext_vector_type(4)));
typedef unsigned int uintx2 __attribute__((ext_vector_type(2)));
typedef unsigned int uint;
typedef unsigned short ushort;
typedef unsigned char uchar;

// float -> bf16 (RNE; inputs finite)
static __device__ __forceinline__ ushort f2bf(float f) {
    uint u = __builtin_bit_cast(uint, f);
    return (ushort)((u + 0x7fffu + ((u >> 16) & 1u)) >> 16);
}

// ---------------------------------------------------------------------------
// Atomic-free CSR build, R13: pairs packed to 4B ((dst&255)<<17 | src, since
// src < 2^17), 8192-edge rank blocks -> (block,bucket) runs ~21 edges = 84B
// (was 5 edges/42B at 2048 granularity -> 2.3x line-dirty amplification,
// R12's 77.5MB WRITE_SIZE on fused_mid).
// ---------------------------------------------------------------------------
__global__ __launch_bounds__(256) void pA_hist(const int* __restrict__ dst,
                                               int* __restrict__ hist,
                                               ushort* __restrict__ rank8) {
    __shared__ int h[NBUCK];
    int tid = threadIdx.x;
    for (int i = tid; i < NBUCK; i += 256) h[i] = 0;
    __syncthreads();
    int eb = blockIdx.x * 8192 + tid;
    #pragma unroll
    for (int k = 0; k < 32; ++k) {
        int e = eb + k * 256;
        if (e < NE) {
            int r = atomicAdd(&h[dst[e] >> 8], 1);
            rank8[e] = (ushort)r;               // rank within (block,bucket)
        }
    }
    __syncthreads();
    int* hrow = hist + blockIdx.x * NBUCK;
    for (int i = tid; i < NBUCK; i += 256) hrow[i] = h[i];
}

// Per-bucket exclusive scan over the 196 block rows: hist -> rel (in place),
// column total -> gt[b]. hist is 306KB, L2-resident.
__global__ __launch_bounds__(256) void pS2_colscan(int* __restrict__ hist,
                                                   int* __restrict__ gt) {
    __shared__ int ps[256];
    int b = blockIdx.x;
    int tid = threadIdx.x;
    int v = (tid < PA_BLOCKS) ? hist[tid * NBUCK + b] : 0;
    ps[tid] = v;
    __syncthreads();
    for (int st = 1; st < 256; st <<= 1) {
        int t = (tid >= st) ? ps[tid - st] : 0;
        __syncthreads();
        ps[tid] += t;
        __syncthreads();
    }
    if (tid < PA_BLOCKS) hist[tid * NBUCK + b] = ps[tid] - v;
    if (tid == 255) gt[b] = ps[255];            // column total
}

// Pass S: exclusive scan of bucket totals -> goff.
__global__ __launch_bounds__(512) void pS_scan(const int* __restrict__ gt,
                                               int* __restrict__ goff) {
    __shared__ int s[512];
    int tid = threadIdx.x;
    int v = (tid < NBUCK) ? gt[tid] : 0;
    s[tid] = v;
    __syncthreads();
    for (int st = 1; st < 512; st <<= 1) {
        int t = (tid >= st) ? s[tid - st] : 0;
        __syncthreads();
        s[tid] += t;
        __syncthreads();
    }
    if (tid < NBUCK) goff[tid] = s[tid] - v;
    if (tid == 0) goff[NBUCK] = NE;
}

// ---------------------------------------------------------------------------
// fused_mid: pB (deterministic 4B-pair scatter) overlapped with conv_x+conv_w.
// pB: lbase[b] = goff[b]+rel_row[b] staged in LDS once; per edge = 3 coalesced
// loads + 1 LDS read + 1 packed store. Zero atomics.
// conv outputs via NT stores (pure streams, no short-term reuse).
// ---------------------------------------------------------------------------
__global__ __launch_bounds__(512) void fused_mid(
        const int* __restrict__ src, const int* __restrict__ dst,
        const ushort* __restrict__ rank8, const int* __restrict__ rel,
        const int* __restrict__ goff, uint* __restrict__ pairs,
        const float* __restrict__ x, ushort* __restrict__ xb, uint* __restrict__ xf8,
        const float* __restrict__ W1l, const float* __restrict__ W1r,
        const float* __restrict__ W2l, const float* __restrict__ W2r,
        ushort* __restrict__ WT1, ushort* __restrict__ WT2) {
    __shared__ int lbase[NBUCK];
    int bid = blockIdx.x;
    int tid = threadIdx.x;
    if (bid < PB_BLOCKS) {
        const int* rel_row = rel + bid * NBUCK;
        for (int i = tid; i < NBUCK; i += 512) lbase[i] = goff[i] + rel_row[i];
        __syncthreads();
        int eb = bid * 8192 + tid;
        #pragma unroll
        for (int k = 0; k < 16; ++k) {
            int e = eb + k * 512;
            if (e < NE) {
                int s = src[e];
                int d = dst[e];
                int b = d >> 8;
                int pos = lbase[b] + (int)rank8[e];
                pairs[pos] = ((uint)(d & 255) << 17) | (uint)s;
            }
        }
    } else if (bid < PB_BLOCKS + CX_BLOCKS) {
        int j = (bid - PB_BLOCKS) * 512 + tid;   // elem group [j*8, j*8+8)
        const float4* xr = (const float4*)x + (size_t)j * 2;
        float4 v0 = xr[0], v1 = xr[1];
        uintx4 ob;
        ob.x = (uint)f2bf(v0.x) | ((uint)f2bf(v0.y) << 16);
        ob.y = (uint)f2bf(v0.z) | ((uint)f2bf(v0.w) << 16);
        ob.z = (uint)f2bf(v1.x) | ((uint)f2bf(v1.y) << 16);
        ob.w = (uint)f2bf(v1.z) | ((uint)f2bf(v1.w) << 16);
        __builtin_nontemporal_store(ob, (uintx4*)xb + j);
        uint pk0 = (uint)__builtin_amdgcn_cvt_pk_fp8_f32(v0.x, v0.y, 0, false);
        pk0 = (uint)__builtin_amdgcn_cvt_pk_fp8_f32(v0.z, v0.w, (int)pk0, true);
        uint pk1 = (uint)__builtin_amdgcn_cvt_pk_fp8_f32(v1.x, v1.y, 0, false);
        pk1 = (uint)__builtin_amdgcn_cvt_pk_fp8_f32(v1.z, v1.w, (int)pk1, true);
        uintx2 pkv = {pk0, pk1};
        __builtin_nontemporal_store(pkv, (uintx2*)xf8 + j);
    } else {
        int id = (bid - PB_BLOCKS - CX_BLOCKS) * 512 + tid;
        int n = id >> 8, k = id & 255;
        float a = (k < 128) ? W1l[k * 128 + n] : W1r[(k - 128) * 128 + n];
        float b = (k < 128) ? W2l[k * 128 + n] : W2r[(k - 128) * 128 + n];
        WT1[id] = f2bf(a);
        WT2[id] = f2bf(b);
    }
}

// Pass C: one block per bucket. LDS degree count + scan -> off[] (coalesced),
// then scatter src into the bucket's ~16KB srt window. pairs read is L2-hot.
__global__ __launch_bounds__(256) void pC_scatter(const uint* __restrict__ pairs,
                                                  const int* __restrict__ goff,
                                                  int* __restrict__ off,
                                                  int* __restrict__ srt) {
    __shared__ int deg[256];
    __shared__ int loc[256];
    int b = blockIdx.x;
    int beg = goff[b], end = goff[b + 1];
    int tid = threadIdx.x;
    deg[tid] = 0;
    __syncthreads();
    for (int i = beg + tid; i < end; i += 256)
        atomicAdd(&deg[pairs[i] >> 17], 1);
    __syncthreads();
    int v = deg[tid];
    loc[tid] = v;
    __syncthreads();
    for (int st = 1; st < 256; st <<= 1) {
        int t = (tid >= st) ? loc[tid - st] : 0;
        __syncthreads();
        loc[tid] += t;
        __syncthreads();
    }
    int excl = loc[tid] - v + beg;     // global CSR offset for node (b<<8)+tid
    int n = (b << 8) + tid;
    if (n < NN) off[n] = excl;
    __syncthreads();
    deg[tid] = excl;                   // reuse as cursor
    __syncthreads();
    for (int i = beg + tid; i < end; i += 256) {
        uint pr = pairs[i];
        int pos = atomicAdd(&deg[pr >> 17], 1);
        srt[pos] = (int)(pr & 0x1FFFFu);
    }
}

// ---------------------------------------------------------------------------
// Mean aggregation, SINGLE PASS over row-major fp8 (R11 design, unchanged).
// ---------------------------------------------------------------------------
static __device__ __forceinline__ void acc16(floatx2* ac, uint4 v) {
    ac[0] += __builtin_amdgcn_cvt_pk_f32_fp8((int)v.x, false);
    ac[1] += __builtin_amdgcn_cvt_pk_f32_fp8((int)v.x, true);
    ac[2] += __builtin_amdgcn_cvt_pk_f32_fp8((int)v.y, false);
    ac[3] += __builtin_amdgcn_cvt_pk_f32_fp8((int)v.y, true);
    ac[4] += __builtin_amdgcn_cvt_pk_f32_fp8((int)v.z, false);
    ac[5] += __builtin_amdgcn_cvt_pk_f32_fp8((int)v.z, true);
    ac[6] += __builtin_amdgcn_cvt_pk_f32_fp8((int)v.w, false);
    ac[7] += __builtin_amdgcn_cvt_pk_f32_fp8((int)v.w, true);
}

#define AGG_LOOP(IDX)                                            \
    {                                                            \
        int i = lb;                                              \
        for (; i + 8 <= le; i += 8) {                            \
            int idx[8];                                          \
            _Pragma("unroll")                                    \
            for (int k = 0; k < 8; ++k) idx[k] = IDX(i + k);     \
            uint4 v[8];                                          \
            _Pragma("unroll")                                    \
            for (int k = 0; k < 8; ++k) v[k] = f[(size_t)idx[k] * 8]; \
            _Pragma("unroll")                                    \
            for (int k = 0; k < 8; ++k) acc16(ac, v[k]);         \
        }                                                        \
        if (i + 4 <= le) {                                       \
            int idx[4];                                          \
            _Pragma("unroll")                                    \
            for (int k = 0; k < 4; ++k) idx[k] = IDX(i + k);     \
            uint4 v[4];                                          \
            _Pragma("unroll")                                    \
            for (int k = 0; k < 4; ++k) v[k] = f[(size_t)idx[k] * 8]; \
            _Pragma("unroll")                                    \
            for (int k = 0; k < 4; ++k) acc16(ac, v[k]);         \
            i += 4;                                              \
        }                                                        \
        for (; i < le; ++i) {                                    \
            uint4 v = f[(size_t)IDX(i) * 8];                     \
            acc16(ac, v);                                        \
        }                                                        \
    }

__global__ __launch_bounds__(256) void agg_csr(const uint* __restrict__ feat8,
                                               const int* __restrict__ srt,
                                               const int* __restrict__ off,
                                               ushort* __restrict__ aggb) {
    __shared__ int sidx[2048];
    int nb = blockIdx.x * 32;
    if (nb >= NN) return;                        // uniform per block
    int tid = threadIdx.x;

    int segb = off[nb];
    int nend = nb + 32;
    int sege = (nend < NN) ? off[nend] : NE;
    int stage = min(sege - segb, 2048);
    for (int i = tid; i < stage; i += 256) sidx[i] = srt[segb + i];
    __syncthreads();

    int n = nb + (tid >> 3);
    int l = tid & 7;
    if (n >= NN) return;
    const uint4* f = (const uint4*)feat8 + l;    // row stride = 8 uint4 (128B)

    int beg = off[n];
    int end = (n < NN - 1) ? off[n + 1] : NE;
    int lb = beg - segb, le = end - segb;

    floatx2 ac[8];
    #pragma unroll
    for (int t = 0; t < 8; ++t) ac[t] = (floatx2){0.f, 0.f};

    if (le <= stage) {
        #define IDX_LDS(ii) sidx[ii]
        AGG_LOOP(IDX_LDS)
        #undef IDX_LDS
    } else {
        #define IDX_GBL(ii) srt[segb + (ii)]
        AGG_LOOP(IDX_GBL)
        #undef IDX_GBL
    }

    float inv = 1.0f / fmaxf((float)(end - beg), 1.0f);
    uintx4 o0, o1;
    o0.x = (uint)f2bf(ac[0].x * inv) | ((uint)f2bf(ac[0].y * inv) << 16);
    o0.y = (uint)f2bf(ac[1].x * inv) | ((uint)f2bf(ac[1].y * inv) << 16);
    o0.z = (uint)f2bf(ac[2].x * inv) | ((uint)f2bf(ac[2].y * inv) << 16);
    o0.w = (uint)f2bf(ac[3].x * inv) | ((uint)f2bf(ac[3].y * inv) << 16);
    o1.x = (uint)f2bf(ac[4].x * inv) | ((uint)f2bf(ac[4].y * inv) << 16);
    o1.y = (uint)f2bf(ac[5].x * inv) | ((uint)f2bf(ac[5].y * inv) << 16);
    o1.z = (uint)f2bf(ac[6].x * inv) | ((uint)f2bf(ac[6].y * inv) << 16);
    o1.w = (uint)f2bf(ac[7].x * inv) | ((uint)f2bf(ac[7].y * inv) << 16);
    uintx4* dp = (uintx4*)(aggb + (size_t)n * 128 + l * 16);
    __builtin_nontemporal_store(o0, dp);
    __builtin_nontemporal_store(o1, dp + 1);
}

// ---------------------------------------------------------------------------
// Fused GEMM: C[n,j] = act( [agg|self][n,:] @ WT[j,:] + bias[j] ), K=256.
// 512 threads = 8 waves, 128 rows/block. WT staged in LDS (XOR swizzle, 64KB).
// F8OUT: emit fp8 ROW-MAJOR (single-pass agg input) -> contiguous epilogue.
// ---------------------------------------------------------------------------
template <int RELU, int BF16OUT, int F8OUT>
__global__ __launch_bounds__(512, 4) void gemm_mfma(
        const ushort* __restrict__ aggb, const ushort* __restrict__ selfb,
        const ushort* __restrict__ WT, const float* __restrict__ bias,
        void* __restrict__ outv, uchar* __restrict__ f8out) {
    __shared__ ushort sWT[128 * 256];            // 64KB, swizzled chunks
    const int tid = threadIdx.x;
    const int blk = blockIdx.x;

    #pragma unroll
    for (int it = 0; it < 8; ++it) {
        int flat = it * 512 + tid;               // 0..4095
        int col = flat >> 5;
        int c = flat & 31;
        uint4 v = *(const uint4*)(WT + (size_t)col * 256 + c * 8);
        *(uint4*)&sWT[col * 256 + (c ^ (col & 7)) * 8] = v;
    }

    const int w = tid >> 6;
    const int lane = tid & 63;
    const int m = lane & 15;
    const int q = lane >> 4;

    int node_m = blk * 128 + w * 16 + m;
    int cn = node_m < NN ? node_m : NN - 1;
    const ushort* arow = aggb + (size_t)cn * 128;
    const ushort* xrow = selfb + (size_t)cn * 128;
    short8 a[8];
    #pragma unroll
    for (int kk = 0; kk < 4; ++kk) {
        a[kk]     = *(const short8*)(arow + kk * 32 + q * 8);
        a[4 + kk] = *(const short8*)(xrow + kk * 32 + q * 8);
    }

    __syncthreads();

    floatx4 acc[8];
    #pragma unroll
    for (int t = 0; t < 8; ++t) acc[t] = (floatx4){0.f, 0.f, 0.f, 0.f};

    const int m7 = m & 7;
    #pragma unroll
    for (int kk = 0; kk < 8; ++kk) {
        int cx = (kk * 4 + q) ^ m7;
        #pragma unroll
        for (int t = 0; t < 8; ++t) {
            short8 b = *(const short8*)&sWT[(t * 16 + m) * 256 + cx * 8];
            acc[t] = __builtin_amdgcn_mfma_f32_16x16x32_bf16(a[kk], b, acc[t], 0, 0, 0);
        }
    }

    const int node_base = blk * 128 + w * 16 + q * 4;
    #pragma unroll
    for (int t = 0; t < 8; ++t) {
        int col = t * 16 + m;
        float bj = bias[col];
        #pragma unroll
        for (int r = 0; r < 4; ++r) {
            int node = node_base + r;
            if (node < NN) {
                float v = acc[t][r] + bj;
                if (RELU) v = fmaxf(v, 0.0f);
                if (BF16OUT)
                    ((ushort*)outv)[(size_t)node * 128 + col] = f2bf(v);
                else
                    ((float*)outv)[(size_t)node * 128 + col] = v;
                if (F8OUT) {
                    uint pk = (uint)__builtin_amdgcn_cvt_pk_fp8_f32(v, v, 0, false);
                    f8out[(size_t)node * 128 + col] = (uchar)pk;
                }
            }
        }
    }
}

// ---------------------------------------------------------------------------
extern "C" void kernel_launch(void* const* d_in, const int* in_sizes, int n_in,
                              void* d_out, int out_size, void* d_ws, size_t ws_size,
                              hipStream_t stream) {
    const float* x   = (const float*)d_in[0];
    const int*   ei  = (const int*)d_in[1];
    const float* W1l = (const float*)d_in[2];
    const float* b1  = (const float*)d_in[3];
    const float* W1r = (const float*)d_in[4];
    const float* W2l = (const float*)d_in[5];
    const float* b2  = (const float*)d_in[6];
    const float* W2r = (const float*)d_in[7];
    float*       out = (float*)d_out;

    const int* src = ei;
    const int* dst = ei + NE;

    // workspace layout (bytes), total 96.93 MB
    char* ws = (char*)d_ws;
    int*    off  = (int*)(ws);                   // 400000
    int*    srt  = (int*)(ws + 400000);          // 6400000 (ends 6.8MB)
    ushort* WT1  = (ushort*)(ws + 7200000);      // 65536
    ushort* WT2  = (ushort*)(ws + 7265536);      // 65536
    ushort* xb   = (ushort*)(ws + 7331072);      // 25600000
    uint*   xf8  = (uint*)(ws + 32931072);       // 12800000 (row-major fp8)
    ushort* aggb = (ushort*)(ws + 45731072);     // 25600000
    ushort* hb   = (ushort*)(ws + 71331072);     // 25600000 (end 96.93MB)
    uchar*  hf8  = (uchar*)xf8;                  // alias: xf8 dead after agg L1
    // CSR-build temporaries (alias aggb region, all dead before agg writes it):
    uint*   pairs = (uint*)aggb;                         // 6400000 (packed 4B)
    int*    hist  = (int*)((char*)aggb + 6400000);       // 196*391*4 = 306544
    ushort* rank8 = (ushort*)((char*)aggb + 6720000);    // 3200000
    int*    gt    = (int*)((char*)aggb + 9920512);       // 1564
    int*    goff  = (int*)((char*)aggb + 9922304);       // 1568

    // ---- CSR build (atomic-free, packed) + input conversion ----
    pA_hist<<<PA_BLOCKS, 256, 0, stream>>>(dst, hist, rank8);
    pS2_colscan<<<NBUCK, 256, 0, stream>>>(hist, gt);
    pS_scan<<<1, 512, 0, stream>>>(gt, goff);
    fused_mid<<<PB_BLOCKS + CX_BLOCKS + CW_BLOCKS, 512, 0, stream>>>(
        src, dst, rank8, hist, goff, pairs, x, xb, xf8,
        W1l, W1r, W2l, W2r, WT1, WT2);
    pC_scatter<<<NBUCK, 256, 0, stream>>>(pairs, goff, off, srt);

    const int gemm_grid = (NN + 127) / 128;

    // ---- layer 1 ----  (single-pass agg: every edge row gathered once)
    agg_csr<<<AGG_GRID, 256, 0, stream>>>(xf8, srt, off, aggb);
    gemm_mfma<1, 1, 1><<<gemm_grid, 512, 0, stream>>>(aggb, xb, WT1, b1, hb, hf8);

    // ---- layer 2 ----
    agg_csr<<<AGG_GRID, 256, 0, stream>>>((const uint*)hf8, srt, off, aggb);
    gemm_mfma<0, 0, 0><<<gemm_grid, 512, 0, stream>>>(aggb, hb, WT2, b2, out, nullptr);
}